// Round 8
// baseline (223.601 us; speedup 1.0000x reference)
//
#include <hip/hip_runtime.h>
#include <hip/hip_bf16.h>
#include <stdint.h>
#include <math.h>

// ---------------------------------------------------------------------------
// JointAttention: dual-stream rmsnorm -> QKV proj -> RoPE -> joint attention
// over concat(a, x) (4096 tokens, 16 q-heads, 4 kv-heads tiled h%4) -> out proj.
// All matmuls in bf16 MFMA, fp32 accumulate.
//
// R16 = R15 + T4 (counted vmcnt) on BOTH attn and the GEMM mainloop:
//  - Every prior barrier was __syncthreads() = vmcnt(0) full drain -- the
//    m233/m218 stall structure. m218: counted-vs-drain0 = +38-73%.
//  - attn: stage-ahead +2 -> +3 tiles (slot (t+3)%4 last read by PV(t-1),
//    one barrier of separation). Per-half sync = s_waitcnt vmcnt(4) + raw
//    s_barrier: the 4 just-issued loads fly across the barrier (~2 halves
//    of flight time). Full drain only before the LDS-scratch combine.
//  - GEMM: 1-step intervals, 4-slot rotation (stage k+2 at step k, 2-step
//    flight), vmcnt(3) + raw barrier per step. Invariant: entering step k,
//    only stage(k+1) is outstanding; step k issues stage(k+2) (6 total),
//    end-of-step vmcnt(3) retires stage(k+1) (needed next step).
//  - sched_barrier(0) fences around asm/barrier (rule #18 hygiene).
// ---------------------------------------------------------------------------

#define NSEQ 2048
#define NJ   4096
#define DIMM 1024

typedef __attribute__((ext_vector_type(4))) float f32x4;
typedef __attribute__((ext_vector_type(8))) short bf16x8;
typedef __attribute__((ext_vector_type(4))) short bf16x4;

__device__ __forceinline__ unsigned short f2bf(float f) {
  union { float f; uint32_t u; } v; v.f = f;
  return (unsigned short)((v.u + 0x7FFFu + ((v.u >> 16) & 1u)) >> 16);
}

__device__ __forceinline__ uint32_t pack2bf(float a, float b) {
  __hip_bfloat162 h = __float22bfloat162_rn(float2{a, b});
  union { __hip_bfloat162 h; uint32_t u; } c; c.h = h;
  return c.u;
}

#if defined(__has_builtin)
#if __has_builtin(__builtin_amdgcn_exp2f)
#define FAST_EXP2(x) __builtin_amdgcn_exp2f(x)
#endif
#endif
#ifndef FAST_EXP2
#define FAST_EXP2(x) exp2f(x)
#endif

// async global->LDS, 16B per lane; LDS dest = wave-uniform base + lane*16
__device__ __forceinline__ void glds16(const void* g, void* l) {
  __builtin_amdgcn_global_load_lds(
      (const __attribute__((address_space(1))) unsigned int*)g,
      (__attribute__((address_space(3))) unsigned int*)l, 16, 0, 0);
}

// counted-vmcnt barrier: retire all but the newest N vmem ops, then barrier.
#define SYNC_VM(N) do {                                                    \
    asm volatile("s_waitcnt vmcnt(" #N ")" ::: "memory");                  \
    __builtin_amdgcn_sched_barrier(0);                                     \
    __builtin_amdgcn_s_barrier();                                          \
    __builtin_amdgcn_sched_barrier(0);                                     \
  } while (0)

// ---------------- fused prep: rope tables + weight cast + rmsnorm ----------
__global__ __launch_bounds__(256) void prep_kernel(
    const float* __restrict__ xa, const float* __restrict__ xx,
    const float* __restrict__ ga, const float* __restrict__ gx,
    const float* __restrict__ wqa, const float* __restrict__ wqx,
    const float* __restrict__ wkva, const float* __restrict__ wkvx,
    const float* __restrict__ woa, const float* __restrict__ wox,
    unsigned short* __restrict__ XN, unsigned short* __restrict__ WQT,
    unsigned short* __restrict__ WKVT, unsigned short* __restrict__ WOT,
    float* __restrict__ cosT, float* __restrict__ sinT) {
  __shared__ float tile[32][33];
  __shared__ float red[4];
  int bid = blockIdx.x, t = threadIdx.x;
  if (bid < 256) {
    int idx = bid * 256 + t;                    // exactly NSEQ*32
    int pos = idx >> 5, i = idx & 31;
    // inv = 10000^(-i/32) = 10^(-i/8): binary exponentiation, f64 HW muls.
    double inv = 1.0;
    if (i & 1)  inv *= 0.74989420933245582;     // 10^(-1/8)
    if (i & 2)  inv *= 0.56234132519034908;     // 10^(-1/4)
    if (i & 4)  inv *= 0.31622776601683794;     // 10^(-1/2)
    if (i & 8)  inv *= 0.1;
    if (i & 16) inv *= 0.01;
    double ang = (double)(2 * pos) * inv;       // t = pos * (4096/2048)
    double rev = ang * 0.15915494309189535;     // /(2*pi)
    rev -= floor(rev);                          // frac in [0,1)
    float rf = (float)rev;
    float c, s;
    asm("v_cos_f32 %0, %1" : "=v"(c) : "v"(rf));  // D = cos(S0*2pi)
    asm("v_sin_f32 %0, %1" : "=v"(s) : "v"(rf));  // D = sin(S0*2pi)
    cosT[idx] = c;
    sinT[idx] = s;
  } else if (bid < 6400) {
    int b = bid - 256;
    int z = b >> 10, yx = b & 1023;
    int n0 = (yx >> 5) * 32, k0 = (yx & 31) * 32;
    int s = z & 1, ty = z >> 1;
    int N = (ty == 1) ? 512 : 1024;
    if (n0 >= N) return;                        // block-uniform
    const float* src = (z == 0) ? wqa : (z == 1) ? wqx : (z == 2) ? wkva
                     : (z == 3) ? wkvx : (z == 4) ? woa : wox;
    unsigned short* dst = (ty == 0) ? WQT + (size_t)s * 1024 * 1024
                        : (ty == 1) ? WKVT + (size_t)s * 512 * 1024
                                    : WOT + (size_t)s * 1024 * 1024;
    int r = t >> 3, c4 = (t & 7) * 4;
    f32x4 v = *(const f32x4*)(src + (size_t)(k0 + r) * N + n0 + c4);
    tile[r][c4 + 0] = v.x; tile[r][c4 + 1] = v.y;
    tile[r][c4 + 2] = v.z; tile[r][c4 + 3] = v.w;
    __syncthreads();
    int nn = t >> 3, kk = (t & 7) * 4;
    bf16x4 o;
    o.x = (short)f2bf(tile[kk + 0][nn]);
    o.y = (short)f2bf(tile[kk + 1][nn]);
    o.z = (short)f2bf(tile[kk + 2][nn]);
    o.w = (short)f2bf(tile[kk + 3][nn]);
    *(bf16x4*)(dst + (size_t)(n0 + nn) * 1024 + k0 + kk) = o;
  } else {
    int b = bid - 6400;
    int s = b >> 11, row = b & 2047;
    const float* src = (s == 0 ? xa : xx) + (size_t)row * DIMM;
    const float* g = (s == 0 ? ga : gx);
    f32x4 v = *(const f32x4*)(src + t * 4);
    float ss = v.x * v.x + v.y * v.y + v.z * v.z + v.w * v.w;
#pragma unroll
    for (int o = 32; o > 0; o >>= 1) ss += __shfl_xor(ss, o, 64);
    if ((t & 63) == 0) red[t >> 6] = ss;
    __syncthreads();
    float tot = red[0] + red[1] + red[2] + red[3];
    float rs = rsqrtf(tot * (1.0f / DIMM) + 1e-6f);
    f32x4 gv = *(const f32x4*)(g + t * 4);
    bf16x4 o;
    o.x = (short)f2bf(v.x * rs * gv.x);
    o.y = (short)f2bf(v.y * rs * gv.y);
    o.z = (short)f2bf(v.z * rs * gv.z);
    o.w = (short)f2bf(v.w * rs * gv.w);
    *(bf16x4*)(XN + ((size_t)s * NSEQ + row) * DIMM + t * 4) = o;
  }
}

// ---- shared 64x128x(K=1024) bf16 NT GEMM mainloop, counted-vmcnt pipe -----
// 4 slots (A 64x32 = 2048 sh, B 128x32 = 4096 sh each; 48 KB). 1-step
// intervals: step k stages slot (k+2)&3 (2-step flight), computes slot k&3,
// ends with vmcnt(3)+barrier (retires stage(k+1), leaves stage(k+2) flying).
__device__ __forceinline__ void gemm64_mainloop(
    const unsigned short* __restrict__ Ag, const unsigned short* __restrict__ Bg,
    unsigned short* As, unsigned short* Bs, f32x4 acc[2][4]) {
  int t = threadIdx.x;
  int lane = t & 63, wid = t >> 6;
  int wm = (wid >> 1) * 32, wn = (wid & 1) * 64;
  int l15 = lane & 15, quad = lane >> 4;
  int srow = t >> 2, sko = (t & 3) * 8;
  const unsigned short* ga = Ag + (size_t)srow * 1024 + sko;
  const unsigned short* gb = Bg + (size_t)srow * 1024 + sko;
  unsigned short* la = As + t * 8;
  unsigned short* lb = Bs + t * 8;
#pragma unroll
  for (int mi = 0; mi < 2; ++mi)
#pragma unroll
    for (int j = 0; j < 4; ++j) acc[mi][j] = (f32x4){0.f, 0.f, 0.f, 0.f};

#define GQ_STAGE(S, KT) do {                                               \
    int k0_ = (KT) * 32;                                                   \
    glds16(ga + k0_, la + (S) * 2048);                                     \
    glds16(gb + k0_, lb + (S) * 4096);                                     \
    glds16(gb + 64 * 1024 + k0_, lb + (S) * 4096 + 2048);                  \
  } while (0)

#define GQ_COMP(S) do {                                                    \
    bf16x8 af[2], bfr[4];                                                  \
    _Pragma("unroll")                                                      \
    for (int mi = 0; mi < 2; ++mi)                                         \
      af[mi] = *(const bf16x8*)(As + (S) * 2048 + (wm + mi * 16 + l15) * 32 + quad * 8); \
    _Pragma("unroll")                                                      \
    for (int j = 0; j < 4; ++j)                                            \
      bfr[j] = *(const bf16x8*)(Bs + (S) * 4096 + (wn + j * 16 + l15) * 32 + quad * 8); \
    _Pragma("unroll")                                                      \
    for (int mi = 0; mi < 2; ++mi)                                         \
      _Pragma("unroll")                                                    \
      for (int j = 0; j < 4; ++j)                                          \
        acc[mi][j] = __builtin_amdgcn_mfma_f32_16x16x32_bf16(af[mi], bfr[j], acc[mi][j], 0, 0, 0); \
  } while (0)

  // prologue: stage 0,1; retire stage(0), leave stage(1) flying.
  GQ_STAGE(0, 0);
  GQ_STAGE(1, 1);
  SYNC_VM(3);
  for (int kq = 0; kq < 32; kq += 4) {
    GQ_STAGE(2, (kq + 2) & 31);
    GQ_COMP(0);
    SYNC_VM(3);
    GQ_STAGE(3, (kq + 3) & 31);
    GQ_COMP(1);
    SYNC_VM(3);
    GQ_STAGE(0, (kq + 4) & 31);   // wrap at end: harmless re-stage
    GQ_COMP(2);
    SYNC_VM(3);
    GQ_STAGE(1, (kq + 5) & 31);
    GQ_COMP(3);
    SYNC_VM(3);
  }
  // drain leftover wrap-stages before epilogue/endpgm
  asm volatile("s_waitcnt vmcnt(0)" ::: "memory");
#undef GQ_STAGE
#undef GQ_COMP
}

// ------ QKV GEMM: A=[an;xn] (4096x1024), N=1536 (Q 1024 | K 256 | V 256) ---
__global__ __launch_bounds__(256) void gemm_qkv_kernel(
    const unsigned short* __restrict__ XN, const unsigned short* __restrict__ WQT,
    const unsigned short* __restrict__ WKVT, const float* __restrict__ cosT,
    const float* __restrict__ sinT, unsigned short* __restrict__ QB,
    unsigned short* __restrict__ KB, unsigned short* __restrict__ VT) {
  __shared__ unsigned short As[4 * 2048], Bs[4 * 4096];   // 48 KB
  int n0 = blockIdx.x * 128, m0 = blockIdx.y * 64;
  int s = (m0 >= 2048) ? 1 : 0;
  const unsigned short* Ag = XN + (size_t)m0 * 1024;
  const unsigned short* Bg = (n0 < 1024)
      ? WQT + (size_t)s * 1024 * 1024 + (size_t)n0 * 1024
      : WKVT + (size_t)s * 512 * 1024 + (size_t)(n0 - 1024) * 1024;
  f32x4 acc[2][4];
  gemm64_mainloop(Ag, Bg, As, Bs, acc);
  int t = threadIdx.x, lane = t & 63, wid = t >> 6;
  int wm = (wid >> 1) * 32, wn = (wid & 1) * 64;
  int l15 = lane & 15, quad = lane >> 4;
  int coln = n0 + wn;                     // 64-aligned -> head-uniform per wave
  if (coln < 1280) {
    bool isq = coln < 1024;
    float sc = isq ? (1.4426950408889634f / 64.0f) : 1.0f;  // 1/64 * log2(e)
    unsigned short* dstBase;
    if (isq) dstBase = QB + (size_t)(coln >> 6) * NJ * 64;
    else     dstBase = KB + (size_t)((coln - 1024) >> 6) * NJ * 64;
#pragma unroll
    for (int mi = 0; mi < 2; ++mi)
#pragma unroll
      for (int r = 0; r < 4; ++r) {
        int jr = m0 + wm + mi * 16 + quad * 4 + r;   // joint row (a:0..2047, x:2048..)
        int pos = jr & 2047;
#pragma unroll
        for (int jp = 0; jp < 2; ++jp) {             // d = jp*16+l15 pairs with d+32
          int i = jp * 16 + l15;
          float c = cosT[pos * 32 + i], sn = sinT[pos * 32 + i];
          float x1 = acc[mi][jp][r], x2 = acc[mi][jp + 2][r];
          dstBase[(size_t)jr * 64 + jp * 16 + l15]      = f2bf((x1 * c - x2 * sn) * sc);
          dstBase[(size_t)jr * 64 + 32 + jp * 16 + l15] = f2bf((x2 * c + x1 * sn) * sc);
        }
      }
  } else {
    // V: write straight to VT[d][jr] -- acc[mi][j][0..3] are 4 consecutive jr
    int cvb = coln - 1280;
#pragma unroll
    for (int mi = 0; mi < 2; ++mi)
#pragma unroll
      for (int j = 0; j < 4; ++j) {
        int d = cvb + j * 16 + l15;                  // 0..255 = hk*64 + dh
        int jr0 = m0 + wm + mi * 16 + quad * 4;
        union { bf16x4 v; uint32_t u[2]; } pv;
        pv.u[0] = pack2bf(acc[mi][j][0], acc[mi][j][1]);
        pv.u[1] = pack2bf(acc[mi][j][2], acc[mi][j][3]);
        *(bf16x4*)(VT + (size_t)d * NJ + jr0) = pv.v;
      }
  }
}

// ------------- flash attention: 128 q-rows x 1 head per block --------------
// R13 fragment layout + counted-vmcnt pipeline. 4 single-tile LDS slots
// (64x64 bf16, linear, XOR-swizzled content), staged via glds16 with
// pre-permuted/pre-swizzled global source (K row g(r), chunk c ^= r&7;
// reads XOR identically -> conflict-free). Stage-ahead +3: half t stages
// tile t+3 into slot (t+3)&3 (last read by PV(t-1), one barrier apart).
// Per-half sync = vmcnt(4) + raw s_barrier: the just-issued 4 loads fly
// across the barrier (~2 halves of flight). Full drain before the combine.
__global__ __launch_bounds__(256, 2) void attn_kernel(
    const unsigned short* __restrict__ QB, const unsigned short* __restrict__ KB,
    const unsigned short* __restrict__ VT, unsigned short* __restrict__ AT) {
  __shared__ __align__(16) unsigned short Ks[4][4096];   // 4 slots x 64x64
  __shared__ __align__(16) unsigned short Vs[4][4096];
  int h = blockIdx.y, qt = blockIdx.x;
  int hk = h & 3;                               // jnp.tile -> kv head = h % 4
  int t = threadIdx.x, lane = t & 63, w = t >> 6;
  int l15 = lane & 15, quad = lane >> 4;
  int qsel = w >> 1, ksel = w & 1;
  int q0 = qt * 128 + qsel * 64;                // wave's q rows: q0 + mi*16 + l15
  bf16x8 qf[4][2];
#pragma unroll
  for (int mi = 0; mi < 4; ++mi) {
    const unsigned short* qp = QB + ((size_t)h * NJ + q0 + mi * 16 + l15) * 64;
    qf[mi][0] = *(const bf16x8*)(qp + quad * 8);
    qf[mi][1] = *(const bf16x8*)(qp + 32 + quad * 8);
  }
  f32x4 oT[4][4];                               // O^T partial: [mi][db]
  f32x4 oL[4];                                  // ones-row accum (row0 = lsum)
#pragma unroll
  for (int mi = 0; mi < 4; ++mi) {
    oL[mi] = (f32x4){0.f, 0.f, 0.f, 0.f};
#pragma unroll
    for (int db = 0; db < 4; ++db) oT[mi][db] = (f32x4){0.f, 0.f, 0.f, 0.f};
  }
  bf16x8 vone;                                  // ones A-frag (row 0 only)
  {
    short one = (l15 == 0) ? (short)0x3F80 : (short)0;
    vone = (bf16x8){one, one, one, one, one, one, one, one};
  }
  const unsigned short* Kg = KB + (size_t)hk * NJ * 64;   // [key][d]
  const unsigned short* Vg = VT + (size_t)hk * 64 * NJ;   // [d][key]
  // ---- glds16 source addresses (per thread, loop-invariant) ----
  int r1 = t >> 3, cx = t & 7;
  int e1 = r1 & 7;
  int c1 = cx ^ e1;                             // swizzled 16B chunk
  int gk1 = 32 * (r1 >> 5) + 8 * ((r1 >> 2) & 3) + 4 * ((r1 >> 4) & 1) + (r1 & 3);
  int r2 = r1 + 32;
  int gk2 = 32 * (r2 >> 5) + 8 * ((r2 >> 2) & 3) + 4 * ((r2 >> 4) & 1) + (r2 & 3);
  const unsigned short* sK1 = Kg + (size_t)gk1 * 64 + c1 * 8;   // +tile*4096
  const unsigned short* sK2 = Kg + (size_t)gk2 * 64 + c1 * 8;
  const unsigned short* sV1 = Vg + (size_t)r1 * NJ + c1 * 8;    // +tile*64
  const unsigned short* sV2 = Vg + (size_t)r2 * NJ + c1 * 8;
  // ---- ds_read addresses (per lane, loop-invariant; + slot*4096 shorts) ----
  int e = l15 & 7;
  int co0 = (quad ^ e) * 8;                     // K lo chunk (d 0..31 quarter)
  int co1 = ((4 + quad) ^ e) * 8;               // K hi chunk
  int cov = (((ksel << 2) | quad) ^ e) * 8;     // V chunk (key half ksel)
  const unsigned short* kf0p = &Ks[0][(2 * ksel * 16 + l15) * 64] + co0;
  const unsigned short* kf0q = &Ks[0][(2 * ksel * 16 + l15) * 64] + co1;
  const unsigned short* kf1p = kf0p + 16 * 64;
  const unsigned short* kf1q = kf0q + 16 * 64;
  const unsigned short* vap0 = &Vs[0][(0 * 16 + l15) * 64] + cov;
  const unsigned short* vap1 = &Vs[0][(1 * 16 + l15) * 64] + cov;
  const unsigned short* vap2 = &Vs[0][(2 * 16 + l15) * 64] + cov;
  const unsigned short* vap3 = &Vs[0][(3 * 16 + l15) * 64] + cov;

  f32x4 sxA[4][2], sxB[4][2];
  bf16x8 pb[4];

#define STAGE(S, T) do {                                                   \
    size_t ko_ = (size_t)(T) * 4096;                                       \
    int vo_ = (T) * 64;                                                    \
    glds16(sK1 + ko_, &Ks[S][0] + t * 8);                                  \
    glds16(sK2 + ko_, &Ks[S][2048] + t * 8);                               \
    glds16(sV1 + vo_, &Vs[S][0] + t * 8);                                  \
    glds16(sV2 + vo_, &Vs[S][2048] + t * 8);                               \
  } while (0)

  // QK only (prologue): tile in slot S -> SX
#define QK4(S, SX) do {                                                    \
    bf16x8 k00 = *(const bf16x8*)(kf0p + (S) * 4096);                      \
    bf16x8 k01 = *(const bf16x8*)(kf0q + (S) * 4096);                      \
    bf16x8 k10 = *(const bf16x8*)(kf1p + (S) * 4096);                      \
    bf16x8 k11 = *(const bf16x8*)(kf1q + (S) * 4096);                      \
    _Pragma("unroll")                                                      \
    for (int mi = 0; mi < 4; ++mi) {                                       \
      f32x4 z0 = (f32x4){0.f, 0.f, 0.f, 0.f};                              \
      z0 = __builtin_amdgcn_mfma_f32_16x16x32_bf16(k00, qf[mi][0], z0, 0, 0, 0); \
      z0 = __builtin_amdgcn_mfma_f32_16x16x32_bf16(k01, qf[mi][1], z0, 0, 0, 0); \
      (SX)[mi][0] = z0;                                                    \
      f32x4 z1 = (f32x4){0.f, 0.f, 0.f, 0.f};                              \
      z1 = __builtin_amdgcn_mfma_f32_16x16x32_bf16(k10, qf[mi][0], z1, 0, 0, 0); \
      z1 = __builtin_amdgcn_mfma_f32_16x16x32_bf16(k11, qf[mi][1], z1, 0, 0, 0); \
      (SX)[mi][1] = z1;                                                    \
    }                                                                      \
  } while (0)

  // interleaved: QK(next tile, slot SQ) -> SXN while exp(SXP) -> pb
#define PHASE_A(SQ, SXN, SXP) do {                                         \
    bf16x8 k00 = *(const bf16x8*)(kf0p + (SQ) * 4096);                     \
    bf16x8 k01 = *(const bf16x8*)(kf0q + (SQ) * 4096);                     \
    bf16x8 k10 = *(const bf16x8*)(kf1p + (SQ) * 4096);                     \
    bf16x8 k11 = *(const bf16x8*)(kf1q + (SQ) * 4096);                     \
    _Pragma("unroll")                                                      \
    for (int mi = 0; mi < 4; ++mi) {                                       \
      f32x4 z0 = (f32x4){0.f, 0.f, 0.f, 0.f};                              \
      z0 = __builtin_amdgcn_mfma_f32_16x16x32_bf16(k00, qf[mi][0], z0, 0, 0, 0); \
      z0 = __builtin_amdgcn_mfma_f32_16x16x32_bf16(k01, qf[mi][1], z0, 0, 0, 0); \
      (SXN)[mi][0] = z0;                                                   \
      f32x4 z1 = (f32x4){0.f, 0.f, 0.f, 0.f};                              \
      z1 = __builtin_amdgcn_mfma_f32_16x16x32_bf16(k10, qf[mi][0], z1, 0, 0, 0); \
      z1 = __builtin_amdgcn_mfma_f32_16x16x32_bf16(k11, qf[mi][1], z1, 0, 0, 0); \
      (SXN)[mi][1] = z1;                                                   \
      union { bf16x8 v; uint32_t u[4]; } pk_;                              \
      pk_.u[0] = pack2bf(FAST_EXP2((SXP)[mi][0][0]), FAST_EXP2((SXP)[mi][0][1])); \
      pk_.u[1] = pack2bf(FAST_EXP2((SXP)[mi][0][2]), FAST_EXP2((SXP)[mi][0][3])); \
      pk_.u[2] = pack2bf(FAST_EXP2((SXP)[mi][1][0]), FAST_EXP2((SXP)[mi][1][1])); \
      pk_.u[3] = pack2bf(FAST_EXP2((SXP)[mi][1][2]), FAST_EXP2((SXP)[mi][1][3])); \
      pb[mi] = pk_.v;                                                      \
    }                                                                      \
  } while (0)

#define PHASE_B(SP) do {                                                   \
    __builtin_amdgcn_s_setprio(1);                                         \
    {                                                                      \
      bf16x8 va0 = *(const bf16x8*)(vap0 + (SP) * 4096);                   \
      bf16x8 va1 = *(const bf16x8*)(vap1 + (SP) * 4096);                   \
      bf16x8 va2 = *(const bf16x8*)(vap2 + (SP) * 4096);                   \
      bf16x8 va3 = *(const bf16x8*)(vap3 + (SP) * 4096);                   \
      _Pragma("unroll")                                                    \
      for (int mi = 0; mi < 4; ++mi) {                                     \
        oT[mi][0] = __builtin_amdgcn_mfma_f32_16x16x32_bf16(va0, pb[mi], oT[mi][0], 0, 0, 0); \
        oT[mi][1] = __builtin_amdgcn_mfma_f32_16x16x32_bf16(va1, pb[mi], oT[mi][1], 0, 0, 0); \
        oT[mi][2] = __builtin_amdgcn_mfma_f32_16x16x32_bf16(va2, pb[mi], oT[mi][2], 0, 0, 0); \
        oT[mi][3] = __builtin_amdgcn_mfma_f32_16x16x32_bf16(va3, pb[mi], oT[mi][3], 0, 0, 0); \
        oL[mi] = __builtin_amdgcn_mfma_f32_16x16x32_bf16(vone, pb[mi], oL[mi], 0, 0, 0); \
      }                                                                    \
    }                                                                      \
    __builtin_amdgcn_s_setprio(0);                                         \
  } while (0)

  // prologue: stage tiles 0,1,2; retire 0,1 (leave 2 flying); QK(0) -> sxA
  STAGE(0, 0);
  STAGE(1, 1);
  STAGE(2, 2);
  SYNC_VM(4);
  QK4(0, sxA);
  for (int P = 0; P < 16; ++P) {
    int tb = 4 * P;
    // half 1: PV(tb)@s0, QK(tb+1)@s1 || exp(tb), stage(tb+3)->s3
    STAGE(3, (tb + 3) & 63);
    PHASE_A(1, sxB, sxA);
    PHASE_B(0);
    SYNC_VM(4);
    // half 2: PV(tb+1)@s1, QK(tb+2)@s2 || exp(tb+1), stage(tb+4)->s0
    STAGE(0, (tb + 4) & 63);
    PHASE_A(2, sxA, sxB);
    PHASE_B(1);
    SYNC_VM(4);
    // half 3: PV(tb+2)@s2, QK(tb+3)@s3 || exp(tb+2), stage(tb+5)->s1
    STAGE(1, (tb + 5) & 63);
    PHASE_A(3, sxB, sxA);
    PHASE_B(2);
    SYNC_VM(4);
    // half 4: PV(tb+3)@s3, QK(tb+4)@s0 || exp(tb+3), stage(tb+6)->s2
    STAGE(2, (tb + 6) & 63);
    PHASE_A(0, sxA, sxB);
    PHASE_B(3);
    SYNC_VM(4);
  }
  // full drain before reusing LDS as combine scratch (in-flight glds16
  // would stomp it)
  __syncthreads();
#undef STAGE
#undef QK4
#undef PHASE_A
#undef PHASE_B

  // ---- combine key-split partials across wave pairs (ksel 0 <- 1) ----
  float ls[4];
#pragma unroll
  for (int mi = 0; mi < 4; ++mi) {
    float s = oL[mi][0];
    s += __shfl_xor(s, 16, 64);
    s += __shfl_xor(s, 32, 64);
    ls[mi] = s;
  }
  // per-qsel scratch: qsel0 -> Ks region (32 KB), qsel1 -> Vs region.
  // oT at lane stride 17 f32x4 (272 B); ls after (offset 64*68 floats).
  float* xb = (qsel == 0) ? (float*)&Ks[0][0] : (float*)&Vs[0][0];
  float* xl = xb + 64 * 68;
  if (ksel == 1) {
    f32x4* dst = (f32x4*)xb + (size_t)lane * 17;
#pragma unroll
    for (int mi = 0; mi < 4; ++mi)
#pragma unroll
      for (int db = 0; db < 4; ++db) dst[mi * 4 + db] = oT[mi][db];
    float* dl = xl + lane * 4;
#pragma unroll
    for (int mi = 0; mi < 4; ++mi) dl[mi] = ls[mi];
  }
  __syncthreads();
  if (ksel == 0) {
    const f32x4* src = (const f32x4*)xb + (size_t)lane * 17;
    const float* sl = xl + lane * 4;
#pragma unroll
    for (int mi = 0; mi < 4; ++mi) {
      float inv = 1.0f / (ls[mi] + sl[mi]);
      int qrow = q0 + mi * 16 + l15;
#pragma unroll
      for (int db = 0; db < 4; ++db) {
        f32x4 o = oT[mi][db] + src[mi * 4 + db];
        union { bf16x4 v; uint32_t u[2]; } ov;
        ov.u[0] = pack2bf(o[0] * inv, o[1] * inv);
        ov.u[1] = pack2bf(o[2] * inv, o[3] * inv);
        *(bf16x4*)(AT + (size_t)qrow * DIMM + h * 64 + db * 16 + quad * 4) = ov.v;
      }
    }
  }
}

// ---------------- output GEMM: AT (4096x1024) @ Wout^T + bias -> f32 -------
__global__ __launch_bounds__(256) void gemm_out_kernel(
    const unsigned short* __restrict__ AT, const unsigned short* __restrict__ WOT,
    const float* __restrict__ ba, const float* __restrict__ bx,
    float* __restrict__ out) {
  __shared__ unsigned short As[4 * 2048], Bs[4 * 4096];   // 48 KB
  int n0 = blockIdx.x * 128, m0 = blockIdx.y * 64;
  int s = (m0 >= 2048) ? 1 : 0;                 // 0 = a-stream rows, 1 = x
  const unsigned short* Ag = AT + (size_t)m0 * 1024;
  const unsigned short* Bg = WOT + (size_t)s * 1024 * 1024 + (size_t)n0 * 1024;
  f32x4 acc[2][4];
  gemm64_mainloop(Ag, Bg, As, Bs, acc);
  int t = threadIdx.x, lane = t & 63, wid = t >> 6;
  int wm = (wid >> 1) * 32, wn = (wid & 1) * 64;
  int l15 = lane & 15, quad = lane >> 4;
  const float* bias = s ? bx : ba;
  // d_out = [out_x (2048x1024) | out_a (2048x1024)]
  float* obase = s ? (out + (size_t)(m0 - 2048) * 1024)
                   : (out + (size_t)2048 * 1024 + (size_t)m0 * 1024);
#pragma unroll
  for (int mi = 0; mi < 2; ++mi)
#pragma unroll
    for (int r = 0; r < 4; ++r) {
      int row = wm + mi * 16 + quad * 4 + r;
#pragma unroll
      for (int j = 0; j < 4; ++j) {
        int col = n0 + wn + j * 16 + l15;
        obase[(size_t)row * 1024 + col] = acc[mi][j][r] + bias[col];
      }
    }
}

// ---------------------------------------------------------------------------
extern "C" void kernel_launch(void* const* d_in, const int* in_sizes, int n_in,
                              void* d_out, int out_size, void* d_ws, size_t ws_size,
                              hipStream_t stream) {
  const float* x      = (const float*)d_in[0];
  const float* a      = (const float*)d_in[1];
  const float* g_x    = (const float*)d_in[2];
  const float* g_a    = (const float*)d_in[3];
  const float* Wq_x   = (const float*)d_in[4];
  const float* Wkv_x  = (const float*)d_in[5];
  const float* Wq_a   = (const float*)d_in[6];
  const float* Wkv_a  = (const float*)d_in[7];
  const float* Wout_x = (const float*)d_in[8];
  const float* bout_x = (const float*)d_in[9];
  const float* Wout_a = (const float*)d_in[10];
  const float* bout_a = (const float*)d_in[11];
  float* out = (float*)d_out;

  // workspace (30.5 MB). AT aliases XN (dead after gemm_qkv).
  char* ws = (char*)d_ws;
  const size_t MB = 1024 * 1024;
  unsigned short* XN   = (unsigned short*)(ws);            // 8 MB
  unsigned short* WQT  = (unsigned short*)(ws + 8 * MB);   // 4 MB
  unsigned short* WKVT = (unsigned short*)(ws + 12 * MB);  // 2 MB
  unsigned short* WOT  = (unsigned short*)(ws + 14 * MB);  // 4 MB
  unsigned short* QB   = (unsigned short*)(ws + 18 * MB);  // 8 MB
  unsigned short* KB   = (unsigned short*)(ws + 26 * MB);  // 2 MB
  unsigned short* VT   = (unsigned short*)(ws + 28 * MB);  // 2 MB
  float* cosT          = (float*)(ws + 30 * MB);           // 256 KB
  float* sinT          = (float*)(ws + 30 * MB + 262144);  // 256 KB
  unsigned short* AT   = XN;                               // alias

  prep_kernel<<<dim3(10496), dim3(256), 0, stream>>>(
      a, x, g_a, g_x, Wq_a, Wq_x, Wkv_a, Wkv_x, Wout_a, Wout_x,
      XN, WQT, WKVT, WOT, cosT, sinT);
  gemm_qkv_kernel<<<dim3(12, 64), dim3(256), 0, stream>>>(
      XN, WQT, WKVT, cosT, sinT, QB, KB, VT);
  attn_kernel<<<dim3(32, 16), dim3(256), 0, stream>>>(QB, KB, VT, AT);
  gemm_out_kernel<<<dim3(8, 64), dim3(256), 0, stream>>>(
      AT, WOT, bout_a, bout_x, out);
}

// Round 9
// 222.879 us; speedup vs baseline: 1.0032x; 1.0032x over previous
//
#include <hip/hip_runtime.h>
#include <hip/hip_bf16.h>
#include <stdint.h>
#include <math.h>

// ---------------------------------------------------------------------------
// JointAttention: dual-stream rmsnorm -> QKV proj -> RoPE -> joint attention
// over concat(a, x) (4096 tokens, 16 q-heads, 4 kv-heads tiled h%4) -> out proj.
// All matmuls in bf16 MFMA, fp32 accumulate.
//
// R17 = R16 with the non-attn residual targeted:
//  - attn is at the m214 plain-HIP ceiling (~915 GF/s) -- unchanged.
//  - gemm_qkv: restored to the m97-verified 128x128 geometry (wave 64x64,
//    acc[4][4], 8 LDS reads : 16 MFMA = 2:1) never before combined with the
//    counted-vmcnt 4-slot pipeline. gemm64 was LDS-pipe-bound (6 reads :
//    8 MFMA -> 864 LDS-cyc vs 460 MFMA-cyc per CU-step).
//  - RoPE tables eliminated: trig (f64 binary-exp 10^(-i/8) + v_cos/v_sin)
//    computed inline in the qkv epilogue (~32 pairs/thread, once/block).
//    prep loses the table branch; cosT/sinT buffers deleted.
//  - gemm_out / attn unchanged from R16.
// ---------------------------------------------------------------------------

#define NSEQ 2048
#define NJ   4096
#define DIMM 1024

typedef __attribute__((ext_vector_type(4))) float f32x4;
typedef __attribute__((ext_vector_type(8))) short bf16x8;
typedef __attribute__((ext_vector_type(4))) short bf16x4;

__device__ __forceinline__ unsigned short f2bf(float f) {
  union { float f; uint32_t u; } v; v.f = f;
  return (unsigned short)((v.u + 0x7FFFu + ((v.u >> 16) & 1u)) >> 16);
}

__device__ __forceinline__ uint32_t pack2bf(float a, float b) {
  __hip_bfloat162 h = __float22bfloat162_rn(float2{a, b});
  union { __hip_bfloat162 h; uint32_t u; } c; c.h = h;
  return c.u;
}

#if defined(__has_builtin)
#if __has_builtin(__builtin_amdgcn_exp2f)
#define FAST_EXP2(x) __builtin_amdgcn_exp2f(x)
#endif
#endif
#ifndef FAST_EXP2
#define FAST_EXP2(x) exp2f(x)
#endif

// async global->LDS, 16B per lane; LDS dest = wave-uniform base + lane*16
__device__ __forceinline__ void glds16(const void* g, void* l) {
  __builtin_amdgcn_global_load_lds(
      (const __attribute__((address_space(1))) unsigned int*)g,
      (__attribute__((address_space(3))) unsigned int*)l, 16, 0, 0);
}

// counted-vmcnt barrier: retire all but the newest N vmem ops, then barrier.
#define SYNC_VM(N) do {                                                    \
    asm volatile("s_waitcnt vmcnt(" #N ")" ::: "memory");                  \
    __builtin_amdgcn_sched_barrier(0);                                     \
    __builtin_amdgcn_s_barrier();                                          \
    __builtin_amdgcn_sched_barrier(0);                                     \
  } while (0)

// rope trig: cos/sin(2*pos * 10^(-i/8)) via f64 binexp + native f32 trig
__device__ __forceinline__ void rope_cs(int pos, int i, float* c, float* s) {
  double inv = 1.0;
  if (i & 1)  inv *= 0.74989420933245582;     // 10^(-1/8)
  if (i & 2)  inv *= 0.56234132519034908;     // 10^(-1/4)
  if (i & 4)  inv *= 0.31622776601683794;     // 10^(-1/2)
  if (i & 8)  inv *= 0.1;
  if (i & 16) inv *= 0.01;
  double rev = (double)(2 * pos) * inv * 0.15915494309189535;
  rev -= floor(rev);
  float rf = (float)rev;
  float cc, ss;
  asm("v_cos_f32 %0, %1" : "=v"(cc) : "v"(rf));  // D = cos(S0*2pi)
  asm("v_sin_f32 %0, %1" : "=v"(ss) : "v"(rf));  // D = sin(S0*2pi)
  *c = cc; *s = ss;
}

// ---------------- fused prep: weight cast+transpose + rmsnorm --------------
// flat grid: [0,6144) transpose f32[1024][N] -> bf16[N][1024];
//            [6144,10240) rmsnorm + bf16 cast
__global__ __launch_bounds__(256) void prep_kernel(
    const float* __restrict__ xa, const float* __restrict__ xx,
    const float* __restrict__ ga, const float* __restrict__ gx,
    const float* __restrict__ wqa, const float* __restrict__ wqx,
    const float* __restrict__ wkva, const float* __restrict__ wkvx,
    const float* __restrict__ woa, const float* __restrict__ wox,
    unsigned short* __restrict__ XN, unsigned short* __restrict__ WQT,
    unsigned short* __restrict__ WKVT, unsigned short* __restrict__ WOT) {
  __shared__ float tile[32][33];
  __shared__ float red[4];
  int bid = blockIdx.x, t = threadIdx.x;
  if (bid < 6144) {
    int b = bid;
    int z = b >> 10, yx = b & 1023;
    int n0 = (yx >> 5) * 32, k0 = (yx & 31) * 32;
    int s = z & 1, ty = z >> 1;
    int N = (ty == 1) ? 512 : 1024;
    if (n0 >= N) return;                        // block-uniform
    const float* src = (z == 0) ? wqa : (z == 1) ? wqx : (z == 2) ? wkva
                     : (z == 3) ? wkvx : (z == 4) ? woa : wox;
    unsigned short* dst = (ty == 0) ? WQT + (size_t)s * 1024 * 1024
                        : (ty == 1) ? WKVT + (size_t)s * 512 * 1024
                                    : WOT + (size_t)s * 1024 * 1024;
    int r = t >> 3, c4 = (t & 7) * 4;
    f32x4 v = *(const f32x4*)(src + (size_t)(k0 + r) * N + n0 + c4);
    tile[r][c4 + 0] = v.x; tile[r][c4 + 1] = v.y;
    tile[r][c4 + 2] = v.z; tile[r][c4 + 3] = v.w;
    __syncthreads();
    int nn = t >> 3, kk = (t & 7) * 4;
    bf16x4 o;
    o.x = (short)f2bf(tile[kk + 0][nn]);
    o.y = (short)f2bf(tile[kk + 1][nn]);
    o.z = (short)f2bf(tile[kk + 2][nn]);
    o.w = (short)f2bf(tile[kk + 3][nn]);
    *(bf16x4*)(dst + (size_t)(n0 + nn) * 1024 + k0 + kk) = o;
  } else {
    int b = bid - 6144;
    int s = b >> 11, row = b & 2047;
    const float* src = (s == 0 ? xa : xx) + (size_t)row * DIMM;
    const float* g = (s == 0 ? ga : gx);
    f32x4 v = *(const f32x4*)(src + t * 4);
    float ss = v.x * v.x + v.y * v.y + v.z * v.z + v.w * v.w;
#pragma unroll
    for (int o = 32; o > 0; o >>= 1) ss += __shfl_xor(ss, o, 64);
    if ((t & 63) == 0) red[t >> 6] = ss;
    __syncthreads();
    float tot = red[0] + red[1] + red[2] + red[3];
    float rs = rsqrtf(tot * (1.0f / DIMM) + 1e-6f);
    f32x4 gv = *(const f32x4*)(g + t * 4);
    bf16x4 o;
    o.x = (short)f2bf(v.x * rs * gv.x);
    o.y = (short)f2bf(v.y * rs * gv.y);
    o.z = (short)f2bf(v.z * rs * gv.z);
    o.w = (short)f2bf(v.w * rs * gv.w);
    *(bf16x4*)(XN + ((size_t)s * NSEQ + row) * DIMM + t * 4) = o;
  }
}

// ------ QKV GEMM: 128x128 tile (m97 geometry) + counted-vmcnt 4-slot pipe --
// A=[an;xn] (4096x1024), N=1536 (Q 1024 | K 256 | V 256). 4 waves, wave =
// 64x64, acc[4][4], 8 LDS reads : 16 MFMA per K-step. Slots 8KB A + 8KB B
// (64 KB total). Step k: stage slot (k+2)&3 (4 glds16), compute slot k&3,
// vmcnt(4)+barrier (retires stage(k+1), leaves stage(k+2) flying).
// Epilogue: RoPE with INLINE trig (no tables); q carries scales+log2(e);
// V written transposed to VT[256][4096].
__global__ __launch_bounds__(256) void gemm_qkv_kernel(
    const unsigned short* __restrict__ XN, const unsigned short* __restrict__ WQT,
    const unsigned short* __restrict__ WKVT, unsigned short* __restrict__ QB,
    unsigned short* __restrict__ KB, unsigned short* __restrict__ VT) {
  __shared__ unsigned short As[4 * 4096], Bs[4 * 4096];   // 64 KB
  int n0 = blockIdx.x * 128, m0 = blockIdx.y * 128;
  int s = (m0 >= 2048) ? 1 : 0;
  const unsigned short* Ag = XN + (size_t)m0 * 1024;
  const unsigned short* Bg = (n0 < 1024)
      ? WQT + (size_t)s * 1024 * 1024 + (size_t)n0 * 1024
      : WKVT + (size_t)s * 512 * 1024 + (size_t)(n0 - 1024) * 1024;
  int t = threadIdx.x;
  int lane = t & 63, wid = t >> 6;
  int wm = (wid >> 1) * 64, wn = (wid & 1) * 64;
  int l15 = lane & 15, quad = lane >> 4;
  int srow = t >> 2, sko = (t & 3) * 8;
  const unsigned short* ga = Ag + (size_t)srow * 1024 + sko;
  const unsigned short* gb = Bg + (size_t)srow * 1024 + sko;
  unsigned short* la = As + t * 8;
  unsigned short* lb = Bs + t * 8;
  f32x4 acc[4][4];
#pragma unroll
  for (int mi = 0; mi < 4; ++mi)
#pragma unroll
    for (int j = 0; j < 4; ++j) acc[mi][j] = (f32x4){0.f, 0.f, 0.f, 0.f};

#define GQ_STAGE(S, KT) do {                                               \
    int k0_ = (KT) * 32;                                                   \
    glds16(ga + k0_, la + (S) * 4096);                                     \
    glds16(ga + 64 * 1024 + k0_, la + (S) * 4096 + 2048);                  \
    glds16(gb + k0_, lb + (S) * 4096);                                     \
    glds16(gb + 64 * 1024 + k0_, lb + (S) * 4096 + 2048);                  \
  } while (0)

#define GQ_COMP(S) do {                                                    \
    bf16x8 af[4], bfr[4];                                                  \
    _Pragma("unroll")                                                      \
    for (int mi = 0; mi < 4; ++mi)                                         \
      af[mi] = *(const bf16x8*)(As + (S) * 4096 + (wm + mi * 16 + l15) * 32 + quad * 8); \
    _Pragma("unroll")                                                      \
    for (int j = 0; j < 4; ++j)                                            \
      bfr[j] = *(const bf16x8*)(Bs + (S) * 4096 + (wn + j * 16 + l15) * 32 + quad * 8); \
    _Pragma("unroll")                                                      \
    for (int mi = 0; mi < 4; ++mi)                                         \
      _Pragma("unroll")                                                    \
      for (int j = 0; j < 4; ++j)                                          \
        acc[mi][j] = __builtin_amdgcn_mfma_f32_16x16x32_bf16(af[mi], bfr[j], acc[mi][j], 0, 0, 0); \
  } while (0)

  GQ_STAGE(0, 0);
  GQ_STAGE(1, 1);
  SYNC_VM(4);
  for (int kq = 0; kq < 32; kq += 4) {
    GQ_STAGE(2, (kq + 2) & 31);
    GQ_COMP(0);
    SYNC_VM(4);
    GQ_STAGE(3, (kq + 3) & 31);
    GQ_COMP(1);
    SYNC_VM(4);
    GQ_STAGE(0, (kq + 4) & 31);   // wrap at end: harmless re-stage
    GQ_COMP(2);
    SYNC_VM(4);
    GQ_STAGE(1, (kq + 5) & 31);
    GQ_COMP(3);
    SYNC_VM(4);
  }
  asm volatile("s_waitcnt vmcnt(0)" ::: "memory");
#undef GQ_STAGE
#undef GQ_COMP

  int coln = n0 + wn;                     // 64-aligned -> head-uniform per wave
  if (coln < 1280) {
    bool isq = coln < 1024;
    float sc = isq ? (1.4426950408889634f / 64.0f) : 1.0f;  // 1/64 * log2(e)
    unsigned short* dstBase;
    if (isq) dstBase = QB + (size_t)(coln >> 6) * NJ * 64;
    else     dstBase = KB + (size_t)((coln - 1024) >> 6) * NJ * 64;
#pragma unroll
    for (int mi = 0; mi < 4; ++mi)
#pragma unroll
      for (int r = 0; r < 4; ++r) {
        int jr = m0 + wm + mi * 16 + quad * 4 + r;   // joint row (a:0..2047, x:2048..)
        int pos = jr & 2047;
#pragma unroll
        for (int jp = 0; jp < 2; ++jp) {             // d = jp*16+l15 pairs with d+32
          int i = jp * 16 + l15;
          float c, sn;
          rope_cs(pos, i, &c, &sn);
          float x1 = acc[mi][jp][r], x2 = acc[mi][jp + 2][r];
          dstBase[(size_t)jr * 64 + jp * 16 + l15]      = f2bf((x1 * c - x2 * sn) * sc);
          dstBase[(size_t)jr * 64 + 32 + jp * 16 + l15] = f2bf((x2 * c + x1 * sn) * sc);
        }
      }
  } else {
    // V: write straight to VT[d][jr] -- acc[mi][j][0..3] are 4 consecutive jr
    int cvb = coln - 1280;
#pragma unroll
    for (int mi = 0; mi < 4; ++mi)
#pragma unroll
      for (int j = 0; j < 4; ++j) {
        int d = cvb + j * 16 + l15;                  // 0..255 = hk*64 + dh
        int jr0 = m0 + wm + mi * 16 + quad * 4;
        union { bf16x4 v; uint32_t u[2]; } pv;
        pv.u[0] = pack2bf(acc[mi][j][0], acc[mi][j][1]);
        pv.u[1] = pack2bf(acc[mi][j][2], acc[mi][j][3]);
        *(bf16x4*)(VT + (size_t)d * NJ + jr0) = pv.v;
      }
  }
}

// ---- shared 64x128x(K=1024) bf16 NT GEMM mainloop, counted-vmcnt pipe -----
// (used by gemm_out: grid (8,64) = 512 blocks = 2/CU)
__device__ __forceinline__ void gemm64_mainloop(
    const unsigned short* __restrict__ Ag, const unsigned short* __restrict__ Bg,
    unsigned short* As, unsigned short* Bs, f32x4 acc[2][4]) {
  int t = threadIdx.x;
  int lane = t & 63, wid = t >> 6;
  int wm = (wid >> 1) * 32, wn = (wid & 1) * 64;
  int l15 = lane & 15, quad = lane >> 4;
  int srow = t >> 2, sko = (t & 3) * 8;
  const unsigned short* ga = Ag + (size_t)srow * 1024 + sko;
  const unsigned short* gb = Bg + (size_t)srow * 1024 + sko;
  unsigned short* la = As + t * 8;
  unsigned short* lb = Bs + t * 8;
#pragma unroll
  for (int mi = 0; mi < 2; ++mi)
#pragma unroll
    for (int j = 0; j < 4; ++j) acc[mi][j] = (f32x4){0.f, 0.f, 0.f, 0.f};

#define GO_STAGE(S, KT) do {                                               \
    int k0_ = (KT) * 32;                                                   \
    glds16(ga + k0_, la + (S) * 2048);                                     \
    glds16(gb + k0_, lb + (S) * 4096);                                     \
    glds16(gb + 64 * 1024 + k0_, lb + (S) * 4096 + 2048);                  \
  } while (0)

#define GO_COMP(S) do {                                                    \
    bf16x8 af[2], bfr[4];                                                  \
    _Pragma("unroll")                                                      \
    for (int mi = 0; mi < 2; ++mi)                                         \
      af[mi] = *(const bf16x8*)(As + (S) * 2048 + (wm + mi * 16 + l15) * 32 + quad * 8); \
    _Pragma("unroll")                                                      \
    for (int j = 0; j < 4; ++j)                                            \
      bfr[j] = *(const bf16x8*)(Bs + (S) * 4096 + (wn + j * 16 + l15) * 32 + quad * 8); \
    _Pragma("unroll")                                                      \
    for (int mi = 0; mi < 2; ++mi)                                         \
      _Pragma("unroll")                                                    \
      for (int j = 0; j < 4; ++j)                                          \
        acc[mi][j] = __builtin_amdgcn_mfma_f32_16x16x32_bf16(af[mi], bfr[j], acc[mi][j], 0, 0, 0); \
  } while (0)

  GO_STAGE(0, 0);
  GO_STAGE(1, 1);
  SYNC_VM(3);
  for (int kq = 0; kq < 32; kq += 4) {
    GO_STAGE(2, (kq + 2) & 31);
    GO_COMP(0);
    SYNC_VM(3);
    GO_STAGE(3, (kq + 3) & 31);
    GO_COMP(1);
    SYNC_VM(3);
    GO_STAGE(0, (kq + 4) & 31);   // wrap at end: harmless re-stage
    GO_COMP(2);
    SYNC_VM(3);
    GO_STAGE(1, (kq + 5) & 31);
    GO_COMP(3);
    SYNC_VM(3);
  }
  asm volatile("s_waitcnt vmcnt(0)" ::: "memory");
#undef GO_STAGE
#undef GO_COMP
}

// ------------- flash attention: 128 q-rows x 1 head per block --------------
// R13 fragment layout + counted-vmcnt pipeline (R16, unchanged). 4 LDS
// slots (64x64 bf16, linear, XOR-swizzled content) staged via glds16 with
// pre-permuted/pre-swizzled global source; reads XOR identically. Stage
// ahead +3; per-half sync = vmcnt(4) + raw s_barrier; full drain before the
// combine.
__global__ __launch_bounds__(256, 2) void attn_kernel(
    const unsigned short* __restrict__ QB, const unsigned short* __restrict__ KB,
    const unsigned short* __restrict__ VT, unsigned short* __restrict__ AT) {
  __shared__ __align__(16) unsigned short Ks[4][4096];   // 4 slots x 64x64
  __shared__ __align__(16) unsigned short Vs[4][4096];
  int h = blockIdx.y, qt = blockIdx.x;
  int hk = h & 3;                               // jnp.tile -> kv head = h % 4
  int t = threadIdx.x, lane = t & 63, w = t >> 6;
  int l15 = lane & 15, quad = lane >> 4;
  int qsel = w >> 1, ksel = w & 1;
  int q0 = qt * 128 + qsel * 64;                // wave's q rows: q0 + mi*16 + l15
  bf16x8 qf[4][2];
#pragma unroll
  for (int mi = 0; mi < 4; ++mi) {
    const unsigned short* qp = QB + ((size_t)h * NJ + q0 + mi * 16 + l15) * 64;
    qf[mi][0] = *(const bf16x8*)(qp + quad * 8);
    qf[mi][1] = *(const bf16x8*)(qp + 32 + quad * 8);
  }
  f32x4 oT[4][4];                               // O^T partial: [mi][db]
  f32x4 oL[4];                                  // ones-row accum (row0 = lsum)
#pragma unroll
  for (int mi = 0; mi < 4; ++mi) {
    oL[mi] = (f32x4){0.f, 0.f, 0.f, 0.f};
#pragma unroll
    for (int db = 0; db < 4; ++db) oT[mi][db] = (f32x4){0.f, 0.f, 0.f, 0.f};
  }
  bf16x8 vone;                                  // ones A-frag (row 0 only)
  {
    short one = (l15 == 0) ? (short)0x3F80 : (short)0;
    vone = (bf16x8){one, one, one, one, one, one, one, one};
  }
  const unsigned short* Kg = KB + (size_t)hk * NJ * 64;   // [key][d]
  const unsigned short* Vg = VT + (size_t)hk * 64 * NJ;   // [d][key]
  // ---- glds16 source addresses (per thread, loop-invariant) ----
  int r1 = t >> 3, cx = t & 7;
  int e1 = r1 & 7;
  int c1 = cx ^ e1;                             // swizzled 16B chunk
  int gk1 = 32 * (r1 >> 5) + 8 * ((r1 >> 2) & 3) + 4 * ((r1 >> 4) & 1) + (r1 & 3);
  int r2 = r1 + 32;
  int gk2 = 32 * (r2 >> 5) + 8 * ((r2 >> 2) & 3) + 4 * ((r2 >> 4) & 1) + (r2 & 3);
  const unsigned short* sK1 = Kg + (size_t)gk1 * 64 + c1 * 8;   // +tile*4096
  const unsigned short* sK2 = Kg + (size_t)gk2 * 64 + c1 * 8;
  const unsigned short* sV1 = Vg + (size_t)r1 * NJ + c1 * 8;    // +tile*64
  const unsigned short* sV2 = Vg + (size_t)r2 * NJ + c1 * 8;
  // ---- ds_read addresses (per lane, loop-invariant; + slot*4096 shorts) ----
  int e = l15 & 7;
  int co0 = (quad ^ e) * 8;                     // K lo chunk (d 0..31 quarter)
  int co1 = ((4 + quad) ^ e) * 8;               // K hi chunk
  int cov = (((ksel << 2) | quad) ^ e) * 8;     // V chunk (key half ksel)
  const unsigned short* kf0p = &Ks[0][(2 * ksel * 16 + l15) * 64] + co0;
  const unsigned short* kf0q = &Ks[0][(2 * ksel * 16 + l15) * 64] + co1;
  const unsigned short* kf1p = kf0p + 16 * 64;
  const unsigned short* kf1q = kf0q + 16 * 64;
  const unsigned short* vap0 = &Vs[0][(0 * 16 + l15) * 64] + cov;
  const unsigned short* vap1 = &Vs[0][(1 * 16 + l15) * 64] + cov;
  const unsigned short* vap2 = &Vs[0][(2 * 16 + l15) * 64] + cov;
  const unsigned short* vap3 = &Vs[0][(3 * 16 + l15) * 64] + cov;

  f32x4 sxA[4][2], sxB[4][2];
  bf16x8 pb[4];

#define STAGE(S, T) do {                                                   \
    size_t ko_ = (size_t)(T) * 4096;                                       \
    int vo_ = (T) * 64;                                                    \
    glds16(sK1 + ko_, &Ks[S][0] + t * 8);                                  \
    glds16(sK2 + ko_, &Ks[S][2048] + t * 8);                               \
    glds16(sV1 + vo_, &Vs[S][0] + t * 8);                                  \
    glds16(sV2 + vo_, &Vs[S][2048] + t * 8);                               \
  } while (0)

  // QK only (prologue): tile in slot S -> SX
#define QK4(S, SX) do {                                                    \
    bf16x8 k00 = *(const bf16x8*)(kf0p + (S) * 4096);                      \
    bf16x8 k01 = *(const bf16x8*)(kf0q + (S) * 4096);                      \
    bf16x8 k10 = *(const bf16x8*)(kf1p + (S) * 4096);                      \
    bf16x8 k11 = *(const bf16x8*)(kf1q + (S) * 4096);                      \
    _Pragma("unroll")                                                      \
    for (int mi = 0; mi < 4; ++mi) {                                       \
      f32x4 z0 = (f32x4){0.f, 0.f, 0.f, 0.f};                              \
      z0 = __builtin_amdgcn_mfma_f32_16x16x32_bf16(k00, qf[mi][0], z0, 0, 0, 0); \
      z0 = __builtin_amdgcn_mfma_f32_16x16x32_bf16(k01, qf[mi][1], z0, 0, 0, 0); \
      (SX)[mi][0] = z0;                                                    \
      f32x4 z1 = (f32x4){0.f, 0.f, 0.f, 0.f};                              \
      z1 = __builtin_amdgcn_mfma_f32_16x16x32_bf16(k10, qf[mi][0], z1, 0, 0, 0); \
      z1 = __builtin_amdgcn_mfma_f32_16x16x32_bf16(k11, qf[mi][1], z1, 0, 0, 0); \
      (SX)[mi][1] = z1;                                                    \
    }                                                                      \
  } while (0)

  // interleaved: QK(next tile, slot SQ) -> SXN while exp(SXP) -> pb
#define PHASE_A(SQ, SXN, SXP) do {                                         \
    bf16x8 k00 = *(const bf16x8*)(kf0p + (SQ) * 4096);                     \
    bf16x8 k01 = *(const bf16x8*)(kf0q + (SQ) * 4096);                     \
    bf16x8 k10 = *(const bf16x8*)(kf1p + (SQ) * 4096);                     \
    bf16x8 k11 = *(const bf16x8*)(kf1q + (SQ) * 4096);                     \
    _Pragma("unroll")                                                      \
    for (int mi = 0; mi < 4; ++mi) {                                       \
      f32x4 z0 = (f32x4){0.f, 0.f, 0.f, 0.f};                              \
      z0 = __builtin_amdgcn_mfma_f32_16x16x32_bf16(k00, qf[mi][0], z0, 0, 0, 0); \
      z0 = __builtin_amdgcn_mfma_f32_16x16x32_bf16(k01, qf[mi][1], z0, 0, 0, 0); \
      (SXN)[mi][0] = z0;                                                   \
      f32x4 z1 = (f32x4){0.f, 0.f, 0.f, 0.f};                              \
      z1 = __builtin_amdgcn_mfma_f32_16x16x32_bf16(k10, qf[mi][0], z1, 0, 0, 0); \
      z1 = __builtin_amdgcn_mfma_f32_16x16x32_bf16(k11, qf[mi][1], z1, 0, 0, 0); \
      (SXN)[mi][1] = z1;                                                   \
      union { bf16x8 v; uint32_t u[4]; } pk_;                              \
      pk_.u[0] = pack2bf(FAST_EXP2((SXP)[mi][0][0]), FAST_EXP2((SXP)[mi][0][1])); \
      pk_.u[1] = pack2bf(FAST_EXP2((SXP)[mi][0][2]), FAST_EXP2((SXP)[mi][0][3])); \
      pk_.u[2] = pack2bf(FAST_EXP2((SXP)[mi][1][0]), FAST_EXP2((SXP)[mi][1][1])); \
      pk_.u[3] = pack2bf(FAST_EXP2((SXP)[mi][1][2]), FAST_EXP2((SXP)[mi][1][3])); \
      pb[mi] = pk_.v;                                                      \
    }                                                                      \
  } while (0)

#define PHASE_B(SP) do {                                                   \
    __builtin_amdgcn_s_setprio(1);                                         \
    {                                                                      \
      bf16x8 va0 = *(const bf16x8*)(vap0 + (SP) * 4096);                   \
      bf16x8 va1 = *(const bf16x8*)(vap1 + (SP) * 4096);                   \
      bf16x8 va2 = *(const bf16x8*)(vap2 + (SP) * 4096);                   \
      bf16x8 va3 = *(const bf16x8*)(vap3 + (SP) * 4096);                   \
      _Pragma("unroll")                                                    \
      for (int mi = 0; mi < 4; ++mi) {                                     \
        oT[mi][0] = __builtin_amdgcn_mfma_f32_16x16x32_bf16(va0, pb[mi], oT[mi][0], 0, 0, 0); \
        oT[mi][1] = __builtin_amdgcn_mfma_f32_16x16x32_bf16(va1, pb[mi], oT[mi][1], 0, 0, 0); \
        oT[mi][2] = __builtin_amdgcn_mfma_f32_16x16x32_bf16(va2, pb[mi], oT[mi][2], 0, 0, 0); \
        oT[mi][3] = __builtin_amdgcn_mfma_f32_16x16x32_bf16(va3, pb[mi], oT[mi][3], 0, 0, 0); \
        oL[mi] = __builtin_amdgcn_mfma_f32_16x16x32_bf16(vone, pb[mi], oL[mi], 0, 0, 0); \
      }                                                                    \
    }                                                                      \
    __builtin_amdgcn_s_setprio(0);                                         \
  } while (0)

  // prologue: stage tiles 0,1,2; retire 0,1 (leave 2 flying); QK(0) -> sxA
  STAGE(0, 0);
  STAGE(1, 1);
  STAGE(2, 2);
  SYNC_VM(4);
  QK4(0, sxA);
  for (int P = 0; P < 16; ++P) {
    int tb = 4 * P;
    // half 1: PV(tb)@s0, QK(tb+1)@s1 || exp(tb), stage(tb+3)->s3
    STAGE(3, (tb + 3) & 63);
    PHASE_A(1, sxB, sxA);
    PHASE_B(0);
    SYNC_VM(4);
    // half 2: PV(tb+1)@s1, QK(tb+2)@s2 || exp(tb+1), stage(tb+4)->s0
    STAGE(0, (tb + 4) & 63);
    PHASE_A(2, sxA, sxB);
    PHASE_B(1);
    SYNC_VM(4);
    // half 3: PV(tb+2)@s2, QK(tb+3)@s3 || exp(tb+2), stage(tb+5)->s1
    STAGE(1, (tb + 5) & 63);
    PHASE_A(3, sxB, sxA);
    PHASE_B(2);
    SYNC_VM(4);
    // half 4: PV(tb+3)@s3, QK(tb+4)@s0 || exp(tb+3), stage(tb+6)->s2
    STAGE(2, (tb + 6) & 63);
    PHASE_A(0, sxA, sxB);
    PHASE_B(3);
    SYNC_VM(4);
  }
  // full drain before reusing LDS as combine scratch (in-flight glds16
  // would stomp it)
  __syncthreads();
#undef STAGE
#undef QK4
#undef PHASE_A
#undef PHASE_B

  // ---- combine key-split partials across wave pairs (ksel 0 <- 1) ----
  float ls[4];
#pragma unroll
  for (int mi = 0; mi < 4; ++mi) {
    float s = oL[mi][0];
    s += __shfl_xor(s, 16, 64);
    s += __shfl_xor(s, 32, 64);
    ls[mi] = s;
  }
  // per-qsel scratch: qsel0 -> Ks region (32 KB), qsel1 -> Vs region.
  // oT at lane stride 17 f32x4 (272 B); ls after (offset 64*68 floats).
  float* xb = (qsel == 0) ? (float*)&Ks[0][0] : (float*)&Vs[0][0];
  float* xl = xb + 64 * 68;
  if (ksel == 1) {
    f32x4* dst = (f32x4*)xb + (size_t)lane * 17;
#pragma unroll
    for (int mi = 0; mi < 4; ++mi)
#pragma unroll
      for (int db = 0; db < 4; ++db) dst[mi * 4 + db] = oT[mi][db];
    float* dl = xl + lane * 4;
#pragma unroll
    for (int mi = 0; mi < 4; ++mi) dl[mi] = ls[mi];
  }
  __syncthreads();
  if (ksel == 0) {
    const f32x4* src = (const f32x4*)xb + (size_t)lane * 17;
    const float* sl = xl + lane * 4;
#pragma unroll
    for (int mi = 0; mi < 4; ++mi) {
      float inv = 1.0f / (ls[mi] + sl[mi]);
      int qrow = q0 + mi * 16 + l15;
#pragma unroll
      for (int db = 0; db < 4; ++db) {
        f32x4 o = oT[mi][db] + src[mi * 4 + db];
        union { bf16x4 v; uint32_t u[2]; } ov;
        ov.u[0] = pack2bf(o[0] * inv, o[1] * inv);
        ov.u[1] = pack2bf(o[2] * inv, o[3] * inv);
        *(bf16x4*)(AT + (size_t)qrow * DIMM + h * 64 + db * 16 + quad * 4) = ov.v;
      }
    }
  }
}

// ---------------- output GEMM: AT (4096x1024) @ Wout^T + bias -> f32 -------
__global__ __launch_bounds__(256) void gemm_out_kernel(
    const unsigned short* __restrict__ AT, const unsigned short* __restrict__ WOT,
    const float* __restrict__ ba, const float* __restrict__ bx,
    float* __restrict__ out) {
  __shared__ unsigned short As[4 * 2048], Bs[4 * 4096];   // 48 KB
  int n0 = blockIdx.x * 128, m0 = blockIdx.y * 64;
  int s = (m0 >= 2048) ? 1 : 0;                 // 0 = a-stream rows, 1 = x
  const unsigned short* Ag = AT + (size_t)m0 * 1024;
  const unsigned short* Bg = WOT + (size_t)s * 1024 * 1024 + (size_t)n0 * 1024;
  f32x4 acc[2][4];
  gemm64_mainloop(Ag, Bg, As, Bs, acc);
  int t = threadIdx.x, lane = t & 63, wid = t >> 6;
  int wm = (wid >> 1) * 32, wn = (wid & 1) * 64;
  int l15 = lane & 15, quad = lane >> 4;
  const float* bias = s ? bx : ba;
  // d_out = [out_x (2048x1024) | out_a (2048x1024)]
  float* obase = s ? (out + (size_t)(m0 - 2048) * 1024)
                   : (out + (size_t)2048 * 1024 + (size_t)m0 * 1024);
#pragma unroll
  for (int mi = 0; mi < 2; ++mi)
#pragma unroll
    for (int r = 0; r < 4; ++r) {
      int row = wm + mi * 16 + quad * 4 + r;
#pragma unroll
      for (int j = 0; j < 4; ++j) {
        int col = n0 + wn + j * 16 + l15;
        obase[(size_t)row * 1024 + col] = acc[mi][j][r] + bias[col];
      }
    }
}

// ---------------------------------------------------------------------------
extern "C" void kernel_launch(void* const* d_in, const int* in_sizes, int n_in,
                              void* d_out, int out_size, void* d_ws, size_t ws_size,
                              hipStream_t stream) {
  const float* x      = (const float*)d_in[0];
  const float* a      = (const float*)d_in[1];
  const float* g_x    = (const float*)d_in[2];
  const float* g_a    = (const float*)d_in[3];
  const float* Wq_x   = (const float*)d_in[4];
  const float* Wkv_x  = (const float*)d_in[5];
  const float* Wq_a   = (const float*)d_in[6];
  const float* Wkv_a  = (const float*)d_in[7];
  const float* Wout_x = (const float*)d_in[8];
  const float* bout_x = (const float*)d_in[9];
  const float* Wout_a = (const float*)d_in[10];
  const float* bout_a = (const float*)d_in[11];
  float* out = (float*)d_out;

  // workspace (30 MB). AT aliases XN (dead after gemm_qkv).
  char* ws = (char*)d_ws;
  const size_t MB = 1024 * 1024;
  unsigned short* XN   = (unsigned short*)(ws);            // 8 MB
  unsigned short* WQT  = (unsigned short*)(ws + 8 * MB);   // 4 MB
  unsigned short* WKVT = (unsigned short*)(ws + 12 * MB);  // 2 MB
  unsigned short* WOT  = (unsigned short*)(ws + 14 * MB);  // 4 MB
  unsigned short* QB   = (unsigned short*)(ws + 18 * MB);  // 8 MB
  unsigned short* KB   = (unsigned short*)(ws + 26 * MB);  // 2 MB
  unsigned short* VT   = (unsigned short*)(ws + 28 * MB);  // 2 MB
  unsigned short* AT   = XN;                               // alias

  prep_kernel<<<dim3(10240), dim3(256), 0, stream>>>(
      a, x, g_a, g_x, Wq_a, Wq_x, Wkv_a, Wkv_x, Wout_a, Wout_x,
      XN, WQT, WKVT, WOT);
  gemm_qkv_kernel<<<dim3(12, 32), dim3(256), 0, stream>>>(
      XN, WQT, WKVT, QB, KB, VT);
  attn_kernel<<<dim3(32, 16), dim3(256), 0, stream>>>(QB, KB, VT, AT);
  gemm_out_kernel<<<dim3(8, 64), dim3(256), 0, stream>>>(
      AT, WOT, bout_a, bout_x, out);
}

// Round 11
// 216.487 us; speedup vs baseline: 1.0329x; 1.0295x over previous
//
#include <hip/hip_runtime.h>
#include <hip/hip_bf16.h>
#include <stdint.h>
#include <math.h>

// ---------------------------------------------------------------------------
// JointAttention: dual-stream rmsnorm -> QKV proj -> RoPE -> joint attention
// over concat(a, x) (4096 tokens, 16 q-heads, 4 kv-heads tiled h%4) -> out proj.
// All matmuls in bf16 MFMA, fp32 accumulate.
//
// R19 = R17 (last passing config, 222.9us) + T1 XCD-chunked block swizzle on
// gemm_qkv / attn / gemm_out:
//  - R18's cooperative fusion FAILED correctness (grid.sync under graph
//    capture / cross-XCD L2 writeback unreliable) -> fusion abandoned.
//  - T1 mechanism: blocks sharing an operand panel are dispatch-consecutive
//    and default round-robin spreads them over 8 XCD L2s. Chunked bijective
//    swizzle (nwg%8==0: swz = (bid%8)*(nwg/8) + bid/8) gives each XCD a
//    contiguous work range: qkv = 4 m-rows (A-panels L2-local, 12x reuse),
//    out = 8 m-rows, attn = 2 full kv-heads (1MB K/V each L2-local).
//  - Pure relabeling; math identical to R17.
// ---------------------------------------------------------------------------

#define NSEQ 2048
#define NJ   4096
#define DIMM 1024

typedef __attribute__((ext_vector_type(4))) float f32x4;
typedef __attribute__((ext_vector_type(8))) short bf16x8;
typedef __attribute__((ext_vector_type(4))) short bf16x4;

__device__ __forceinline__ unsigned short f2bf(float f) {
  union { float f; uint32_t u; } v; v.f = f;
  return (unsigned short)((v.u + 0x7FFFu + ((v.u >> 16) & 1u)) >> 16);
}

__device__ __forceinline__ uint32_t pack2bf(float a, float b) {
  __hip_bfloat162 h = __float22bfloat162_rn(float2{a, b});
  union { __hip_bfloat162 h; uint32_t u; } c; c.h = h;
  return c.u;
}

#if defined(__has_builtin)
#if __has_builtin(__builtin_amdgcn_exp2f)
#define FAST_EXP2(x) __builtin_amdgcn_exp2f(x)
#endif
#endif
#ifndef FAST_EXP2
#define FAST_EXP2(x) exp2f(x)
#endif

// async global->LDS, 16B per lane; LDS dest = wave-uniform base + lane*16
__device__ __forceinline__ void glds16(const void* g, void* l) {
  __builtin_amdgcn_global_load_lds(
      (const __attribute__((address_space(1))) unsigned int*)g,
      (__attribute__((address_space(3))) unsigned int*)l, 16, 0, 0);
}

// counted-vmcnt barrier: retire all but the newest N vmem ops, then barrier.
#define SYNC_VM(N) do {                                                    \
    asm volatile("s_waitcnt vmcnt(" #N ")" ::: "memory");                  \
    __builtin_amdgcn_sched_barrier(0);                                     \
    __builtin_amdgcn_s_barrier();                                          \
    __builtin_amdgcn_sched_barrier(0);                                     \
  } while (0)

// rope trig: cos/sin(2*pos * 10^(-i/8)) via f64 binexp + native f32 trig
__device__ __forceinline__ void rope_cs(int pos, int i, float* c, float* s) {
  double inv = 1.0;
  if (i & 1)  inv *= 0.74989420933245582;     // 10^(-1/8)
  if (i & 2)  inv *= 0.56234132519034908;     // 10^(-1/4)
  if (i & 4)  inv *= 0.31622776601683794;     // 10^(-1/2)
  if (i & 8)  inv *= 0.1;
  if (i & 16) inv *= 0.01;
  double rev = (double)(2 * pos) * inv * 0.15915494309189535;
  rev -= floor(rev);
  float rf = (float)rev;
  float cc, ss;
  asm("v_cos_f32 %0, %1" : "=v"(cc) : "v"(rf));  // D = cos(S0*2pi)
  asm("v_sin_f32 %0, %1" : "=v"(ss) : "v"(rf));  // D = sin(S0*2pi)
  *c = cc; *s = ss;
}

// ---------------- fused prep: weight cast+transpose + rmsnorm --------------
// flat grid: [0,6144) transpose f32[1024][N] -> bf16[N][1024];
//            [6144,10240) rmsnorm + bf16 cast
__global__ __launch_bounds__(256) void prep_kernel(
    const float* __restrict__ xa, const float* __restrict__ xx,
    const float* __restrict__ ga, const float* __restrict__ gx,
    const float* __restrict__ wqa, const float* __restrict__ wqx,
    const float* __restrict__ wkva, const float* __restrict__ wkvx,
    const float* __restrict__ woa, const float* __restrict__ wox,
    unsigned short* __restrict__ XN, unsigned short* __restrict__ WQT,
    unsigned short* __restrict__ WKVT, unsigned short* __restrict__ WOT) {
  __shared__ float tile[32][33];
  __shared__ float red[4];
  int bid = blockIdx.x, t = threadIdx.x;
  if (bid < 6144) {
    int b = bid;
    int z = b >> 10, yx = b & 1023;
    int n0 = (yx >> 5) * 32, k0 = (yx & 31) * 32;
    int s = z & 1, ty = z >> 1;
    int N = (ty == 1) ? 512 : 1024;
    if (n0 >= N) return;                        // block-uniform
    const float* src = (z == 0) ? wqa : (z == 1) ? wqx : (z == 2) ? wkva
                     : (z == 3) ? wkvx : (z == 4) ? woa : wox;
    unsigned short* dst = (ty == 0) ? WQT + (size_t)s * 1024 * 1024
                        : (ty == 1) ? WKVT + (size_t)s * 512 * 1024
                                    : WOT + (size_t)s * 1024 * 1024;
    int r = t >> 3, c4 = (t & 7) * 4;
    f32x4 v = *(const f32x4*)(src + (size_t)(k0 + r) * N + n0 + c4);
    tile[r][c4 + 0] = v.x; tile[r][c4 + 1] = v.y;
    tile[r][c4 + 2] = v.z; tile[r][c4 + 3] = v.w;
    __syncthreads();
    int nn = t >> 3, kk = (t & 7) * 4;
    bf16x4 o;
    o.x = (short)f2bf(tile[kk + 0][nn]);
    o.y = (short)f2bf(tile[kk + 1][nn]);
    o.z = (short)f2bf(tile[kk + 2][nn]);
    o.w = (short)f2bf(tile[kk + 3][nn]);
    *(bf16x4*)(dst + (size_t)(n0 + nn) * 1024 + k0 + kk) = o;
  } else {
    int b = bid - 6144;
    int s = b >> 11, row = b & 2047;
    const float* src = (s == 0 ? xa : xx) + (size_t)row * DIMM;
    const float* g = (s == 0 ? ga : gx);
    f32x4 v = *(const f32x4*)(src + t * 4);
    float ss = v.x * v.x + v.y * v.y + v.z * v.z + v.w * v.w;
#pragma unroll
    for (int o = 32; o > 0; o >>= 1) ss += __shfl_xor(ss, o, 64);
    if ((t & 63) == 0) red[t >> 6] = ss;
    __syncthreads();
    float tot = red[0] + red[1] + red[2] + red[3];
    float rs = rsqrtf(tot * (1.0f / DIMM) + 1e-6f);
    f32x4 gv = *(const f32x4*)(g + t * 4);
    bf16x4 o;
    o.x = (short)f2bf(v.x * rs * gv.x);
    o.y = (short)f2bf(v.y * rs * gv.y);
    o.z = (short)f2bf(v.z * rs * gv.z);
    o.w = (short)f2bf(v.w * rs * gv.w);
    *(bf16x4*)(XN + ((size_t)s * NSEQ + row) * DIMM + t * 4) = o;
  }
}

// ------ QKV GEMM: 128x128 tile (m97 geometry) + counted-vmcnt 4-slot pipe --
// 1D grid 384, T1 chunked swizzle: swz = (bid%8)*48 + bid/8 -> each XCD owns
// 48 contiguous works = 4 m-rows x 12 n (A-panels L2-local, 12x reuse).
// Epilogue: RoPE with inline trig; q carries scales+log2(e); V transposed.
__global__ __launch_bounds__(256) void gemm_qkv_kernel(
    const unsigned short* __restrict__ XN, const unsigned short* __restrict__ WQT,
    const unsigned short* __restrict__ WKVT, unsigned short* __restrict__ QB,
    unsigned short* __restrict__ KB, unsigned short* __restrict__ VT) {
  __shared__ unsigned short As[4 * 4096], Bs[4 * 4096];   // 64 KB
  int bid = blockIdx.x;
  int swz = (bid & 7) * 48 + (bid >> 3);        // bijective: 384 % 8 == 0
  int n0 = (swz % 12) * 128, m0 = (swz / 12) * 128;
  int s = (m0 >= 2048) ? 1 : 0;
  const unsigned short* Ag = XN + (size_t)m0 * 1024;
  const unsigned short* Bg = (n0 < 1024)
      ? WQT + (size_t)s * 1024 * 1024 + (size_t)n0 * 1024
      : WKVT + (size_t)s * 512 * 1024 + (size_t)(n0 - 1024) * 1024;
  int t = threadIdx.x;
  int lane = t & 63, wid = t >> 6;
  int wm = (wid >> 1) * 64, wn = (wid & 1) * 64;
  int l15 = lane & 15, quad = lane >> 4;
  int srow = t >> 2, sko = (t & 3) * 8;
  const unsigned short* ga = Ag + (size_t)srow * 1024 + sko;
  const unsigned short* gb = Bg + (size_t)srow * 1024 + sko;
  unsigned short* la = As + t * 8;
  unsigned short* lb = Bs + t * 8;
  f32x4 acc[4][4];
#pragma unroll
  for (int mi = 0; mi < 4; ++mi)
#pragma unroll
    for (int j = 0; j < 4; ++j) acc[mi][j] = (f32x4){0.f, 0.f, 0.f, 0.f};

#define GQ_STAGE(S, KT) do {                                               \
    int k0_ = (KT) * 32;                                                   \
    glds16(ga + k0_, la + (S) * 4096);                                     \
    glds16(ga + 64 * 1024 + k0_, la + (S) * 4096 + 2048);                  \
    glds16(gb + k0_, lb + (S) * 4096);                                     \
    glds16(gb + 64 * 1024 + k0_, lb + (S) * 4096 + 2048);                  \
  } while (0)

#define GQ_COMP(S) do {                                                    \
    bf16x8 af[4], bfr[4];                                                  \
    _Pragma("unroll")                                                      \
    for (int mi = 0; mi < 4; ++mi)                                         \
      af[mi] = *(const bf16x8*)(As + (S) * 4096 + (wm + mi * 16 + l15) * 32 + quad * 8); \
    _Pragma("unroll")                                                      \
    for (int j = 0; j < 4; ++j)                                            \
      bfr[j] = *(const bf16x8*)(Bs + (S) * 4096 + (wn + j * 16 + l15) * 32 + quad * 8); \
    _Pragma("unroll")                                                      \
    for (int mi = 0; mi < 4; ++mi)                                         \
      _Pragma("unroll")                                                    \
      for (int j = 0; j < 4; ++j)                                          \
        acc[mi][j] = __builtin_amdgcn_mfma_f32_16x16x32_bf16(af[mi], bfr[j], acc[mi][j], 0, 0, 0); \
  } while (0)

  GQ_STAGE(0, 0);
  GQ_STAGE(1, 1);
  SYNC_VM(4);
  for (int kq = 0; kq < 32; kq += 4) {
    GQ_STAGE(2, (kq + 2) & 31);
    GQ_COMP(0);
    SYNC_VM(4);
    GQ_STAGE(3, (kq + 3) & 31);
    GQ_COMP(1);
    SYNC_VM(4);
    GQ_STAGE(0, (kq + 4) & 31);   // wrap at end: harmless re-stage
    GQ_COMP(2);
    SYNC_VM(4);
    GQ_STAGE(1, (kq + 5) & 31);
    GQ_COMP(3);
    SYNC_VM(4);
  }
  asm volatile("s_waitcnt vmcnt(0)" ::: "memory");
#undef GQ_STAGE
#undef GQ_COMP

  int coln = n0 + wn;                     // 64-aligned -> head-uniform per wave
  if (coln < 1280) {
    bool isq = coln < 1024;
    float sc = isq ? (1.4426950408889634f / 64.0f) : 1.0f;  // 1/64 * log2(e)
    unsigned short* dstBase;
    if (isq) dstBase = QB + (size_t)(coln >> 6) * NJ * 64;
    else     dstBase = KB + (size_t)((coln - 1024) >> 6) * NJ * 64;
#pragma unroll
    for (int mi = 0; mi < 4; ++mi)
#pragma unroll
      for (int r = 0; r < 4; ++r) {
        int jr = m0 + wm + mi * 16 + quad * 4 + r;   // joint row (a:0..2047, x:2048..)
        int pos = jr & 2047;
#pragma unroll
        for (int jp = 0; jp < 2; ++jp) {             // d = jp*16+l15 pairs with d+32
          int i = jp * 16 + l15;
          float c, sn;
          rope_cs(pos, i, &c, &sn);
          float x1 = acc[mi][jp][r], x2 = acc[mi][jp + 2][r];
          dstBase[(size_t)jr * 64 + jp * 16 + l15]      = f2bf((x1 * c - x2 * sn) * sc);
          dstBase[(size_t)jr * 64 + 32 + jp * 16 + l15] = f2bf((x2 * c + x1 * sn) * sc);
        }
      }
  } else {
    // V: write straight to VT[d][jr] -- acc[mi][j][0..3] are 4 consecutive jr
    int cvb = coln - 1280;
#pragma unroll
    for (int mi = 0; mi < 4; ++mi)
#pragma unroll
      for (int j = 0; j < 4; ++j) {
        int d = cvb + j * 16 + l15;                  // 0..255 = hk*64 + dh
        int jr0 = m0 + wm + mi * 16 + quad * 4;
        union { bf16x4 v; uint32_t u[2]; } pv;
        pv.u[0] = pack2bf(acc[mi][j][0], acc[mi][j][1]);
        pv.u[1] = pack2bf(acc[mi][j][2], acc[mi][j][3]);
        *(bf16x4*)(VT + (size_t)d * NJ + jr0) = pv.v;
      }
  }
}

// ---- shared 64x128x(K=1024) bf16 NT GEMM mainloop, counted-vmcnt pipe -----
__device__ __forceinline__ void gemm64_mainloop(
    const unsigned short* __restrict__ Ag, const unsigned short* __restrict__ Bg,
    unsigned short* As, unsigned short* Bs, f32x4 acc[2][4]) {
  int t = threadIdx.x;
  int lane = t & 63, wid = t >> 6;
  int wm = (wid >> 1) * 32, wn = (wid & 1) * 64;
  int l15 = lane & 15, quad = lane >> 4;
  int srow = t >> 2, sko = (t & 3) * 8;
  const unsigned short* ga = Ag + (size_t)srow * 1024 + sko;
  const unsigned short* gb = Bg + (size_t)srow * 1024 + sko;
  unsigned short* la = As + t * 8;
  unsigned short* lb = Bs + t * 8;
#pragma unroll
  for (int mi = 0; mi < 2; ++mi)
#pragma unroll
    for (int j = 0; j < 4; ++j) acc[mi][j] = (f32x4){0.f, 0.f, 0.f, 0.f};

#define GO_STAGE(S, KT) do {                                               \
    int k0_ = (KT) * 32;                                                   \
    glds16(ga + k0_, la + (S) * 2048);                                     \
    glds16(gb + k0_, lb + (S) * 4096);                                     \
    glds16(gb + 64 * 1024 + k0_, lb + (S) * 4096 + 2048);                  \
  } while (0)

#define GO_COMP(S) do {                                                    \
    bf16x8 af[2], bfr[4];                                                  \
    _Pragma("unroll")                                                      \
    for (int mi = 0; mi < 2; ++mi)                                         \
      af[mi] = *(const bf16x8*)(As + (S) * 2048 + (wm + mi * 16 + l15) * 32 + quad * 8); \
    _Pragma("unroll")                                                      \
    for (int j = 0; j < 4; ++j)                                            \
      bfr[j] = *(const bf16x8*)(Bs + (S) * 4096 + (wn + j * 16 + l15) * 32 + quad * 8); \
    _Pragma("unroll")                                                      \
    for (int mi = 0; mi < 2; ++mi)                                         \
      _Pragma("unroll")                                                    \
      for (int j = 0; j < 4; ++j)                                          \
        acc[mi][j] = __builtin_amdgcn_mfma_f32_16x16x32_bf16(af[mi], bfr[j], acc[mi][j], 0, 0, 0); \
  } while (0)

  GO_STAGE(0, 0);
  GO_STAGE(1, 1);
  SYNC_VM(3);
  for (int kq = 0; kq < 32; kq += 4) {
    GO_STAGE(2, (kq + 2) & 31);
    GO_COMP(0);
    SYNC_VM(3);
    GO_STAGE(3, (kq + 3) & 31);
    GO_COMP(1);
    SYNC_VM(3);
    GO_STAGE(0, (kq + 4) & 31);   // wrap at end: harmless re-stage
    GO_COMP(2);
    SYNC_VM(3);
    GO_STAGE(1, (kq + 5) & 31);
    GO_COMP(3);
    SYNC_VM(3);
  }
  asm volatile("s_waitcnt vmcnt(0)" ::: "memory");
#undef GO_STAGE
#undef GO_COMP
}

// ------------- flash attention: 128 q-rows x 1 head per block --------------
// R13 fragment layout + counted-vmcnt pipeline. 1D grid 512, T1 chunked
// swizzle: swz = (bid%8)*64 + bid/8 -> each XCD owns 64 contiguous works =
// 2 full heads (their 1MB K/V L2-local across 32 blocks each).
__global__ __launch_bounds__(256, 2) void attn_kernel(
    const unsigned short* __restrict__ QB, const unsigned short* __restrict__ KB,
    const unsigned short* __restrict__ VT, unsigned short* __restrict__ AT) {
  __shared__ __align__(16) unsigned short Ks[4][4096];   // 4 slots x 64x64
  __shared__ __align__(16) unsigned short Vs[4][4096];
  int bid = blockIdx.x;
  int swz = (bid & 7) * 64 + (bid >> 3);        // bijective: 512 % 8 == 0
  int qt = swz & 31, h = swz >> 5;
  int hk = h & 3;                               // jnp.tile -> kv head = h % 4
  int t = threadIdx.x, lane = t & 63, w = t >> 6;
  int l15 = lane & 15, quad = lane >> 4;
  int qsel = w >> 1, ksel = w & 1;
  int q0 = qt * 128 + qsel * 64;                // wave's q rows: q0 + mi*16 + l15
  bf16x8 qf[4][2];
#pragma unroll
  for (int mi = 0; mi < 4; ++mi) {
    const unsigned short* qp = QB + ((size_t)h * NJ + q0 + mi * 16 + l15) * 64;
    qf[mi][0] = *(const bf16x8*)(qp + quad * 8);
    qf[mi][1] = *(const bf16x8*)(qp + 32 + quad * 8);
  }
  f32x4 oT[4][4];                               // O^T partial: [mi][db]
  f32x4 oL[4];                                  // ones-row accum (row0 = lsum)
#pragma unroll
  for (int mi = 0; mi < 4; ++mi) {
    oL[mi] = (f32x4){0.f, 0.f, 0.f, 0.f};
#pragma unroll
    for (int db = 0; db < 4; ++db) oT[mi][db] = (f32x4){0.f, 0.f, 0.f, 0.f};
  }
  bf16x8 vone;                                  // ones A-frag (row 0 only)
  {
    short one = (l15 == 0) ? (short)0x3F80 : (short)0;
    vone = (bf16x8){one, one, one, one, one, one, one, one};
  }
  const unsigned short* Kg = KB + (size_t)hk * NJ * 64;   // [key][d]
  const unsigned short* Vg = VT + (size_t)hk * 64 * NJ;   // [d][key]
  // ---- glds16 source addresses (per thread, loop-invariant) ----
  int r1 = t >> 3, cx = t & 7;
  int e1 = r1 & 7;
  int c1 = cx ^ e1;                             // swizzled 16B chunk
  int gk1 = 32 * (r1 >> 5) + 8 * ((r1 >> 2) & 3) + 4 * ((r1 >> 4) & 1) + (r1 & 3);
  int r2 = r1 + 32;
  int gk2 = 32 * (r2 >> 5) + 8 * ((r2 >> 2) & 3) + 4 * ((r2 >> 4) & 1) + (r2 & 3);
  const unsigned short* sK1 = Kg + (size_t)gk1 * 64 + c1 * 8;   // +tile*4096
  const unsigned short* sK2 = Kg + (size_t)gk2 * 64 + c1 * 8;
  const unsigned short* sV1 = Vg + (size_t)r1 * NJ + c1 * 8;    // +tile*64
  const unsigned short* sV2 = Vg + (size_t)r2 * NJ + c1 * 8;
  // ---- ds_read addresses (per lane, loop-invariant; + slot*4096 shorts) ----
  int e = l15 & 7;
  int co0 = (quad ^ e) * 8;                     // K lo chunk (d 0..31 quarter)
  int co1 = ((4 + quad) ^ e) * 8;               // K hi chunk
  int cov = (((ksel << 2) | quad) ^ e) * 8;     // V chunk (key half ksel)
  const unsigned short* kf0p = &Ks[0][(2 * ksel * 16 + l15) * 64] + co0;
  const unsigned short* kf0q = &Ks[0][(2 * ksel * 16 + l15) * 64] + co1;
  const unsigned short* kf1p = kf0p + 16 * 64;
  const unsigned short* kf1q = kf0q + 16 * 64;
  const unsigned short* vap0 = &Vs[0][(0 * 16 + l15) * 64] + cov;
  const unsigned short* vap1 = &Vs[0][(1 * 16 + l15) * 64] + cov;
  const unsigned short* vap2 = &Vs[0][(2 * 16 + l15) * 64] + cov;
  const unsigned short* vap3 = &Vs[0][(3 * 16 + l15) * 64] + cov;

  f32x4 sxA[4][2], sxB[4][2];
  bf16x8 pb[4];

#define STAGE(S, T) do {                                                   \
    size_t ko_ = (size_t)(T) * 4096;                                       \
    int vo_ = (T) * 64;                                                    \
    glds16(sK1 + ko_, &Ks[S][0] + t * 8);                                  \
    glds16(sK2 + ko_, &Ks[S][2048] + t * 8);                               \
    glds16(sV1 + vo_, &Vs[S][0] + t * 8);                                  \
    glds16(sV2 + vo_, &Vs[S][2048] + t * 8);                               \
  } while (0)

  // QK only (prologue): tile in slot S -> SX
#define QK4(S, SX) do {                                                    \
    bf16x8 k00 = *(const bf16x8*)(kf0p + (S) * 4096);                      \
    bf16x8 k01 = *(const bf16x8*)(kf0q + (S) * 4096);                      \
    bf16x8 k10 = *(const bf16x8*)(kf1p + (S) * 4096);                      \
    bf16x8 k11 = *(const bf16x8*)(kf1q + (S) * 4096);                      \
    _Pragma("unroll")                                                      \
    for (int mi = 0; mi < 4; ++mi) {                                       \
      f32x4 z0 = (f32x4){0.f, 0.f, 0.f, 0.f};                              \
      z0 = __builtin_amdgcn_mfma_f32_16x16x32_bf16(k00, qf[mi][0], z0, 0, 0, 0); \
      z0 = __builtin_amdgcn_mfma_f32_16x16x32_bf16(k01, qf[mi][1], z0, 0, 0, 0); \
      (SX)[mi][0] = z0;                                                    \
      f32x4 z1 = (f32x4){0.f, 0.f, 0.f, 0.f};                              \
      z1 = __builtin_amdgcn_mfma_f32_16x16x32_bf16(k10, qf[mi][0], z1, 0, 0, 0); \
      z1 = __builtin_amdgcn_mfma_f32_16x16x32_bf16(k11, qf[mi][1], z1, 0, 0, 0); \
      (SX)[mi][1] = z1;                                                    \
    }                                                                      \
  } while (0)

  // interleaved: QK(next tile, slot SQ) -> SXN while exp(SXP) -> pb
#define PHASE_A(SQ, SXN, SXP) do {                                         \
    bf16x8 k00 = *(const bf16x8*)(kf0p + (SQ) * 4096);                     \
    bf16x8 k01 = *(const bf16x8*)(kf0q + (SQ) * 4096);                     \
    bf16x8 k10 = *(const bf16x8*)(kf1p + (SQ) * 4096);                     \
    bf16x8 k11 = *(const bf16x8*)(kf1q + (SQ) * 4096);                     \
    _Pragma("unroll")                                                      \
    for (int mi = 0; mi < 4; ++mi) {                                       \
      f32x4 z0 = (f32x4){0.f, 0.f, 0.f, 0.f};                              \
      z0 = __builtin_amdgcn_mfma_f32_16x16x32_bf16(k00, qf[mi][0], z0, 0, 0, 0); \
      z0 = __builtin_amdgcn_mfma_f32_16x16x32_bf16(k01, qf[mi][1], z0, 0, 0, 0); \
      (SXN)[mi][0] = z0;                                                   \
      f32x4 z1 = (f32x4){0.f, 0.f, 0.f, 0.f};                              \
      z1 = __builtin_amdgcn_mfma_f32_16x16x32_bf16(k10, qf[mi][0], z1, 0, 0, 0); \
      z1 = __builtin_amdgcn_mfma_f32_16x16x32_bf16(k11, qf[mi][1], z1, 0, 0, 0); \
      (SXN)[mi][1] = z1;                                                   \
      union { bf16x8 v; uint32_t u[4]; } pk_;                              \
      pk_.u[0] = pack2bf(FAST_EXP2((SXP)[mi][0][0]), FAST_EXP2((SXP)[mi][0][1])); \
      pk_.u[1] = pack2bf(FAST_EXP2((SXP)[mi][0][2]), FAST_EXP2((SXP)[mi][0][3])); \
      pk_.u[2] = pack2bf(FAST_EXP2((SXP)[mi][1][0]), FAST_EXP2((SXP)[mi][1][1])); \
      pk_.u[3] = pack2bf(FAST_EXP2((SXP)[mi][1][2]), FAST_EXP2((SXP)[mi][1][3])); \
      pb[mi] = pk_.v;                                                      \
    }                                                                      \
  } while (0)

#define PHASE_B(SP) do {                                                   \
    __builtin_amdgcn_s_setprio(1);                                         \
    {                                                                      \
      bf16x8 va0 = *(const bf16x8*)(vap0 + (SP) * 4096);                   \
      bf16x8 va1 = *(const bf16x8*)(vap1 + (SP) * 4096);                   \
      bf16x8 va2 = *(const bf16x8*)(vap2 + (SP) * 4096);                   \
      bf16x8 va3 = *(const bf16x8*)(vap3 + (SP) * 4096);                   \
      _Pragma("unroll")                                                    \
      for (int mi = 0; mi < 4; ++mi) {                                     \
        oT[mi][0] = __builtin_amdgcn_mfma_f32_16x16x32_bf16(va0, pb[mi], oT[mi][0], 0, 0, 0); \
        oT[mi][1] = __builtin_amdgcn_mfma_f32_16x16x32_bf16(va1, pb[mi], oT[mi][1], 0, 0, 0); \
        oT[mi][2] = __builtin_amdgcn_mfma_f32_16x16x32_bf16(va2, pb[mi], oT[mi][2], 0, 0, 0); \
        oT[mi][3] = __builtin_amdgcn_mfma_f32_16x16x32_bf16(va3, pb[mi], oT[mi][3], 0, 0, 0); \
        oL[mi] = __builtin_amdgcn_mfma_f32_16x16x32_bf16(vone, pb[mi], oL[mi], 0, 0, 0); \
      }                                                                    \
    }                                                                      \
    __builtin_amdgcn_s_setprio(0);                                         \
  } while (0)

  // prologue: stage tiles 0,1,2; retire 0,1 (leave 2 flying); QK(0) -> sxA
  STAGE(0, 0);
  STAGE(1, 1);
  STAGE(2, 2);
  SYNC_VM(4);
  QK4(0, sxA);
  for (int P = 0; P < 16; ++P) {
    int tb = 4 * P;
    // half 1: PV(tb)@s0, QK(tb+1)@s1 || exp(tb), stage(tb+3)->s3
    STAGE(3, (tb + 3) & 63);
    PHASE_A(1, sxB, sxA);
    PHASE_B(0);
    SYNC_VM(4);
    // half 2: PV(tb+1)@s1, QK(tb+2)@s2 || exp(tb+1), stage(tb+4)->s0
    STAGE(0, (tb + 4) & 63);
    PHASE_A(2, sxA, sxB);
    PHASE_B(1);
    SYNC_VM(4);
    // half 3: PV(tb+2)@s2, QK(tb+3)@s3 || exp(tb+2), stage(tb+5)->s1
    STAGE(1, (tb + 5) & 63);
    PHASE_A(3, sxB, sxA);
    PHASE_B(2);
    SYNC_VM(4);
    // half 4: PV(tb+3)@s3, QK(tb+4)@s0 || exp(tb+3), stage(tb+6)->s2
    STAGE(2, (tb + 6) & 63);
    PHASE_A(0, sxA, sxB);
    PHASE_B(3);
    SYNC_VM(4);
  }
  // full drain before reusing LDS as combine scratch (in-flight glds16
  // would stomp it)
  __syncthreads();
#undef STAGE
#undef QK4
#undef PHASE_A
#undef PHASE_B

  // ---- combine key-split partials across wave pairs (ksel 0 <- 1) ----
  float ls[4];
#pragma unroll
  for (int mi = 0; mi < 4; ++mi) {
    float s = oL[mi][0];
    s += __shfl_xor(s, 16, 64);
    s += __shfl_xor(s, 32, 64);
    ls[mi] = s;
  }
  // per-qsel scratch: qsel0 -> Ks region (32 KB), qsel1 -> Vs region.
  // oT at lane stride 17 f32x4 (272 B); ls after (offset 64*68 floats).
  float* xb = (qsel == 0) ? (float*)&Ks[0][0] : (float*)&Vs[0][0];
  float* xl = xb + 64 * 68;
  if (ksel == 1) {
    f32x4* dst = (f32x4*)xb + (size_t)lane * 17;
#pragma unroll
    for (int mi = 0; mi < 4; ++mi)
#pragma unroll
      for (int db = 0; db < 4; ++db) dst[mi * 4 + db] = oT[mi][db];
    float* dl = xl + lane * 4;
#pragma unroll
    for (int mi = 0; mi < 4; ++mi) dl[mi] = ls[mi];
  }
  __syncthreads();
  if (ksel == 0) {
    const f32x4* src = (const f32x4*)xb + (size_t)lane * 17;
    const float* sl = xl + lane * 4;
#pragma unroll
    for (int mi = 0; mi < 4; ++mi) {
      float inv = 1.0f / (ls[mi] + sl[mi]);
      int qrow = q0 + mi * 16 + l15;
#pragma unroll
      for (int db = 0; db < 4; ++db) {
        f32x4 o = oT[mi][db] + src[mi * 4 + db];
        union { bf16x4 v; uint32_t u[2]; } ov;
        ov.u[0] = pack2bf(o[0] * inv, o[1] * inv);
        ov.u[1] = pack2bf(o[2] * inv, o[3] * inv);
        *(bf16x4*)(AT + (size_t)qrow * DIMM + h * 64 + db * 16 + quad * 4) = ov.v;
      }
    }
  }
}

// ---------------- output GEMM: AT (4096x1024) @ Wout^T + bias -> f32 -------
// 1D grid 512, T1 chunked swizzle: each XCD owns 64 contiguous works =
// 8 m-rows x 8 n (A-panels L2-local, 8x reuse).
__global__ __launch_bounds__(256) void gemm_out_kernel(
    const unsigned short* __restrict__ AT, const unsigned short* __restrict__ WOT,
    const float* __restrict__ ba, const float* __restrict__ bx,
    float* __restrict__ out) {
  __shared__ unsigned short As[4 * 2048], Bs[4 * 4096];   // 48 KB
  int bid = blockIdx.x;
  int swz = (bid & 7) * 64 + (bid >> 3);        // bijective: 512 % 8 == 0
  int n0 = (swz & 7) * 128, m0 = (swz >> 3) * 64;
  int s = (m0 >= 2048) ? 1 : 0;                 // 0 = a-stream rows, 1 = x
  const unsigned short* Ag = AT + (size_t)m0 * 1024;
  const unsigned short* Bg = WOT + (size_t)s * 1024 * 1024 + (size_t)n0 * 1024;
  f32x4 acc[2][4];
  gemm64_mainloop(Ag, Bg, As, Bs, acc);
  int t = threadIdx.x, lane = t & 63, wid = t >> 6;
  int wm = (wid >> 1) * 32, wn = (wid & 1) * 64;
  int l15 = lane & 15, quad = lane >> 4;
  const float* bias = s ? bx : ba;
  // d_out = [out_x (2048x1024) | out_a (2048x1024)]
  float* obase = s ? (out + (size_t)(m0 - 2048) * 1024)
                   : (out + (size_t)2048 * 1024 + (size_t)m0 * 1024);
#pragma unroll
  for (int mi = 0; mi < 2; ++mi)
#pragma unroll
    for (int r = 0; r < 4; ++r) {
      int row = wm + mi * 16 + quad * 4 + r;
#pragma unroll
      for (int j = 0; j < 4; ++j) {
        int col = n0 + wn + j * 16 + l15;
        obase[(size_t)row * 1024 + col] = acc[mi][j][r] + bias[col];
      }
    }
}

// ---------------------------------------------------------------------------
extern "C" void kernel_launch(void* const* d_in, const int* in_sizes, int n_in,
                              void* d_out, int out_size, void* d_ws, size_t ws_size,
                              hipStream_t stream) {
  const float* x      = (const float*)d_in[0];
  const float* a      = (const float*)d_in[1];
  const float* g_x    = (const float*)d_in[2];
  const float* g_a    = (const float*)d_in[3];
  const float* Wq_x   = (const float*)d_in[4];
  const float* Wkv_x  = (const float*)d_in[5];
  const float* Wq_a   = (const float*)d_in[6];
  const float* Wkv_a  = (const float*)d_in[7];
  const float* Wout_x = (const float*)d_in[8];
  const float* bout_x = (const float*)d_in[9];
  const float* Wout_a = (const float*)d_in[10];
  const float* bout_a = (const float*)d_in[11];
  float* out = (float*)d_out;

  // workspace (30 MB). AT aliases XN (dead after gemm_qkv).
  char* ws = (char*)d_ws;
  const size_t MB = 1024 * 1024;
  unsigned short* XN   = (unsigned short*)(ws);            // 8 MB
  unsigned short* WQT  = (unsigned short*)(ws + 8 * MB);   // 4 MB
  unsigned short* WKVT = (unsigned short*)(ws + 12 * MB);  // 2 MB
  unsigned short* WOT  = (unsigned short*)(ws + 14 * MB);  // 4 MB
  unsigned short* QB   = (unsigned short*)(ws + 18 * MB);  // 8 MB
  unsigned short* KB   = (unsigned short*)(ws + 26 * MB);  // 2 MB
  unsigned short* VT   = (unsigned short*)(ws + 28 * MB);  // 2 MB
  unsigned short* AT   = XN;                               // alias

  prep_kernel<<<dim3(10240), dim3(256), 0, stream>>>(
      a, x, g_a, g_x, Wq_a, Wq_x, Wkv_a, Wkv_x, Wout_a, Wout_x,
      XN, WQT, WKVT, WOT);
  gemm_qkv_kernel<<<dim3(384), dim3(256), 0, stream>>>(
      XN, WQT, WKVT, QB, KB, VT);
  attn_kernel<<<dim3(512), dim3(256), 0, stream>>>(QB, KB, VT, AT);
  gemm_out_kernel<<<dim3(512), dim3(256), 0, stream>>>(
      AT, WOT, bout_a, bout_x, out);
}

// Round 12
// 215.453 us; speedup vs baseline: 1.0378x; 1.0048x over previous
//
#include <hip/hip_runtime.h>
#include <hip/hip_bf16.h>
#include <stdint.h>
#include <math.h>

// ---------------------------------------------------------------------------
// JointAttention: dual-stream rmsnorm -> QKV proj -> RoPE -> joint attention
// over concat(a, x) (4096 tokens, 16 q-heads, 4 kv-heads tiled h%4) -> out proj.
// All matmuls in bf16 MFMA, fp32 accumulate.
//
// R20 = R19 (best passing, 216.5us: T1 swizzle confirmed -40% attn FETCH)
// + T5 s_setprio around the GEMM MFMA clusters:
//  - The counted-vmcnt slot pipeline (R16/R17) created phase-split wave
//    roles in the GEMMs (stage-issuing vs MFMA-entering) -- exactly the
//    structure m218b showed T5 needs (+21-25%; null only on lockstep).
//    Our GEMMs never had it; attn already does (PHASE_B).
//  - Everything else byte-identical to R19.
// ---------------------------------------------------------------------------

#define NSEQ 2048
#define NJ   4096
#define DIMM 1024

typedef __attribute__((ext_vector_type(4))) float f32x4;
typedef __attribute__((ext_vector_type(8))) short bf16x8;
typedef __attribute__((ext_vector_type(4))) short bf16x4;

__device__ __forceinline__ unsigned short f2bf(float f) {
  union { float f; uint32_t u; } v; v.f = f;
  return (unsigned short)((v.u + 0x7FFFu + ((v.u >> 16) & 1u)) >> 16);
}

__device__ __forceinline__ uint32_t pack2bf(float a, float b) {
  __hip_bfloat162 h = __float22bfloat162_rn(float2{a, b});
  union { __hip_bfloat162 h; uint32_t u; } c; c.h = h;
  return c.u;
}

#if defined(__has_builtin)
#if __has_builtin(__builtin_amdgcn_exp2f)
#define FAST_EXP2(x) __builtin_amdgcn_exp2f(x)
#endif
#endif
#ifndef FAST_EXP2
#define FAST_EXP2(x) exp2f(x)
#endif

// async global->LDS, 16B per lane; LDS dest = wave-uniform base + lane*16
__device__ __forceinline__ void glds16(const void* g, void* l) {
  __builtin_amdgcn_global_load_lds(
      (const __attribute__((address_space(1))) unsigned int*)g,
      (__attribute__((address_space(3))) unsigned int*)l, 16, 0, 0);
}

// counted-vmcnt barrier: retire all but the newest N vmem ops, then barrier.
#define SYNC_VM(N) do {                                                    \
    asm volatile("s_waitcnt vmcnt(" #N ")" ::: "memory");                  \
    __builtin_amdgcn_sched_barrier(0);                                     \
    __builtin_amdgcn_s_barrier();                                          \
    __builtin_amdgcn_sched_barrier(0);                                     \
  } while (0)

// rope trig: cos/sin(2*pos * 10^(-i/8)) via f64 binexp + native f32 trig
__device__ __forceinline__ void rope_cs(int pos, int i, float* c, float* s) {
  double inv = 1.0;
  if (i & 1)  inv *= 0.74989420933245582;     // 10^(-1/8)
  if (i & 2)  inv *= 0.56234132519034908;     // 10^(-1/4)
  if (i & 4)  inv *= 0.31622776601683794;     // 10^(-1/2)
  if (i & 8)  inv *= 0.1;
  if (i & 16) inv *= 0.01;
  double rev = (double)(2 * pos) * inv * 0.15915494309189535;
  rev -= floor(rev);
  float rf = (float)rev;
  float cc, ss;
  asm("v_cos_f32 %0, %1" : "=v"(cc) : "v"(rf));  // D = cos(S0*2pi)
  asm("v_sin_f32 %0, %1" : "=v"(ss) : "v"(rf));  // D = sin(S0*2pi)
  *c = cc; *s = ss;
}

// ---------------- fused prep: weight cast+transpose + rmsnorm --------------
// flat grid: [0,6144) transpose f32[1024][N] -> bf16[N][1024];
//            [6144,10240) rmsnorm + bf16 cast
__global__ __launch_bounds__(256) void prep_kernel(
    const float* __restrict__ xa, const float* __restrict__ xx,
    const float* __restrict__ ga, const float* __restrict__ gx,
    const float* __restrict__ wqa, const float* __restrict__ wqx,
    const float* __restrict__ wkva, const float* __restrict__ wkvx,
    const float* __restrict__ woa, const float* __restrict__ wox,
    unsigned short* __restrict__ XN, unsigned short* __restrict__ WQT,
    unsigned short* __restrict__ WKVT, unsigned short* __restrict__ WOT) {
  __shared__ float tile[32][33];
  __shared__ float red[4];
  int bid = blockIdx.x, t = threadIdx.x;
  if (bid < 6144) {
    int b = bid;
    int z = b >> 10, yx = b & 1023;
    int n0 = (yx >> 5) * 32, k0 = (yx & 31) * 32;
    int s = z & 1, ty = z >> 1;
    int N = (ty == 1) ? 512 : 1024;
    if (n0 >= N) return;                        // block-uniform
    const float* src = (z == 0) ? wqa : (z == 1) ? wqx : (z == 2) ? wkva
                     : (z == 3) ? wkvx : (z == 4) ? woa : wox;
    unsigned short* dst = (ty == 0) ? WQT + (size_t)s * 1024 * 1024
                        : (ty == 1) ? WKVT + (size_t)s * 512 * 1024
                                    : WOT + (size_t)s * 1024 * 1024;
    int r = t >> 3, c4 = (t & 7) * 4;
    f32x4 v = *(const f32x4*)(src + (size_t)(k0 + r) * N + n0 + c4);
    tile[r][c4 + 0] = v.x; tile[r][c4 + 1] = v.y;
    tile[r][c4 + 2] = v.z; tile[r][c4 + 3] = v.w;
    __syncthreads();
    int nn = t >> 3, kk = (t & 7) * 4;
    bf16x4 o;
    o.x = (short)f2bf(tile[kk + 0][nn]);
    o.y = (short)f2bf(tile[kk + 1][nn]);
    o.z = (short)f2bf(tile[kk + 2][nn]);
    o.w = (short)f2bf(tile[kk + 3][nn]);
    *(bf16x4*)(dst + (size_t)(n0 + nn) * 1024 + k0 + kk) = o;
  } else {
    int b = bid - 6144;
    int s = b >> 11, row = b & 2047;
    const float* src = (s == 0 ? xa : xx) + (size_t)row * DIMM;
    const float* g = (s == 0 ? ga : gx);
    f32x4 v = *(const f32x4*)(src + t * 4);
    float ss = v.x * v.x + v.y * v.y + v.z * v.z + v.w * v.w;
#pragma unroll
    for (int o = 32; o > 0; o >>= 1) ss += __shfl_xor(ss, o, 64);
    if ((t & 63) == 0) red[t >> 6] = ss;
    __syncthreads();
    float tot = red[0] + red[1] + red[2] + red[3];
    float rs = rsqrtf(tot * (1.0f / DIMM) + 1e-6f);
    f32x4 gv = *(const f32x4*)(g + t * 4);
    bf16x4 o;
    o.x = (short)f2bf(v.x * rs * gv.x);
    o.y = (short)f2bf(v.y * rs * gv.y);
    o.z = (short)f2bf(v.z * rs * gv.z);
    o.w = (short)f2bf(v.w * rs * gv.w);
    *(bf16x4*)(XN + ((size_t)s * NSEQ + row) * DIMM + t * 4) = o;
  }
}

// ------ QKV GEMM: 128x128 tile (m97 geometry) + counted-vmcnt 4-slot pipe --
// 1D grid 384, T1 chunked swizzle: swz = (bid%8)*48 + bid/8 -> each XCD owns
// 48 contiguous works = 4 m-rows x 12 n (A-panels L2-local, 12x reuse).
// T5: setprio(1) around the MFMA cluster (phase-split waves -> scheduler
// can favor MFMA-entering waves). Epilogue: RoPE inline trig; V transposed.
__global__ __launch_bounds__(256) void gemm_qkv_kernel(
    const unsigned short* __restrict__ XN, const unsigned short* __restrict__ WQT,
    const unsigned short* __restrict__ WKVT, unsigned short* __restrict__ QB,
    unsigned short* __restrict__ KB, unsigned short* __restrict__ VT) {
  __shared__ unsigned short As[4 * 4096], Bs[4 * 4096];   // 64 KB
  int bid = blockIdx.x;
  int swz = (bid & 7) * 48 + (bid >> 3);        // bijective: 384 % 8 == 0
  int n0 = (swz % 12) * 128, m0 = (swz / 12) * 128;
  int s = (m0 >= 2048) ? 1 : 0;
  const unsigned short* Ag = XN + (size_t)m0 * 1024;
  const unsigned short* Bg = (n0 < 1024)
      ? WQT + (size_t)s * 1024 * 1024 + (size_t)n0 * 1024
      : WKVT + (size_t)s * 512 * 1024 + (size_t)(n0 - 1024) * 1024;
  int t = threadIdx.x;
  int lane = t & 63, wid = t >> 6;
  int wm = (wid >> 1) * 64, wn = (wid & 1) * 64;
  int l15 = lane & 15, quad = lane >> 4;
  int srow = t >> 2, sko = (t & 3) * 8;
  const unsigned short* ga = Ag + (size_t)srow * 1024 + sko;
  const unsigned short* gb = Bg + (size_t)srow * 1024 + sko;
  unsigned short* la = As + t * 8;
  unsigned short* lb = Bs + t * 8;
  f32x4 acc[4][4];
#pragma unroll
  for (int mi = 0; mi < 4; ++mi)
#pragma unroll
    for (int j = 0; j < 4; ++j) acc[mi][j] = (f32x4){0.f, 0.f, 0.f, 0.f};

#define GQ_STAGE(S, KT) do {                                               \
    int k0_ = (KT) * 32;                                                   \
    glds16(ga + k0_, la + (S) * 4096);                                     \
    glds16(ga + 64 * 1024 + k0_, la + (S) * 4096 + 2048);                  \
    glds16(gb + k0_, lb + (S) * 4096);                                     \
    glds16(gb + 64 * 1024 + k0_, lb + (S) * 4096 + 2048);                  \
  } while (0)

#define GQ_COMP(S) do {                                                    \
    bf16x8 af[4], bfr[4];                                                  \
    _Pragma("unroll")                                                      \
    for (int mi = 0; mi < 4; ++mi)                                         \
      af[mi] = *(const bf16x8*)(As + (S) * 4096 + (wm + mi * 16 + l15) * 32 + quad * 8); \
    _Pragma("unroll")                                                      \
    for (int j = 0; j < 4; ++j)                                            \
      bfr[j] = *(const bf16x8*)(Bs + (S) * 4096 + (wn + j * 16 + l15) * 32 + quad * 8); \
    __builtin_amdgcn_s_setprio(1);                                         \
    _Pragma("unroll")                                                      \
    for (int mi = 0; mi < 4; ++mi)                                         \
      _Pragma("unroll")                                                    \
      for (int j = 0; j < 4; ++j)                                          \
        acc[mi][j] = __builtin_amdgcn_mfma_f32_16x16x32_bf16(af[mi], bfr[j], acc[mi][j], 0, 0, 0); \
    __builtin_amdgcn_s_setprio(0);                                         \
  } while (0)

  GQ_STAGE(0, 0);
  GQ_STAGE(1, 1);
  SYNC_VM(4);
  for (int kq = 0; kq < 32; kq += 4) {
    GQ_STAGE(2, (kq + 2) & 31);
    GQ_COMP(0);
    SYNC_VM(4);
    GQ_STAGE(3, (kq + 3) & 31);
    GQ_COMP(1);
    SYNC_VM(4);
    GQ_STAGE(0, (kq + 4) & 31);   // wrap at end: harmless re-stage
    GQ_COMP(2);
    SYNC_VM(4);
    GQ_STAGE(1, (kq + 5) & 31);
    GQ_COMP(3);
    SYNC_VM(4);
  }
  asm volatile("s_waitcnt vmcnt(0)" ::: "memory");
#undef GQ_STAGE
#undef GQ_COMP

  int coln = n0 + wn;                     // 64-aligned -> head-uniform per wave
  if (coln < 1280) {
    bool isq = coln < 1024;
    float sc = isq ? (1.4426950408889634f / 64.0f) : 1.0f;  // 1/64 * log2(e)
    unsigned short* dstBase;
    if (isq) dstBase = QB + (size_t)(coln >> 6) * NJ * 64;
    else     dstBase = KB + (size_t)((coln - 1024) >> 6) * NJ * 64;
#pragma unroll
    for (int mi = 0; mi < 4; ++mi)
#pragma unroll
      for (int r = 0; r < 4; ++r) {
        int jr = m0 + wm + mi * 16 + quad * 4 + r;   // joint row (a:0..2047, x:2048..)
        int pos = jr & 2047;
#pragma unroll
        for (int jp = 0; jp < 2; ++jp) {             // d = jp*16+l15 pairs with d+32
          int i = jp * 16 + l15;
          float c, sn;
          rope_cs(pos, i, &c, &sn);
          float x1 = acc[mi][jp][r], x2 = acc[mi][jp + 2][r];
          dstBase[(size_t)jr * 64 + jp * 16 + l15]      = f2bf((x1 * c - x2 * sn) * sc);
          dstBase[(size_t)jr * 64 + 32 + jp * 16 + l15] = f2bf((x2 * c + x1 * sn) * sc);
        }
      }
  } else {
    // V: write straight to VT[d][jr] -- acc[mi][j][0..3] are 4 consecutive jr
    int cvb = coln - 1280;
#pragma unroll
    for (int mi = 0; mi < 4; ++mi)
#pragma unroll
      for (int j = 0; j < 4; ++j) {
        int d = cvb + j * 16 + l15;                  // 0..255 = hk*64 + dh
        int jr0 = m0 + wm + mi * 16 + quad * 4;
        union { bf16x4 v; uint32_t u[2]; } pv;
        pv.u[0] = pack2bf(acc[mi][j][0], acc[mi][j][1]);
        pv.u[1] = pack2bf(acc[mi][j][2], acc[mi][j][3]);
        *(bf16x4*)(VT + (size_t)d * NJ + jr0) = pv.v;
      }
  }
}

// ---- shared 64x128x(K=1024) bf16 NT GEMM mainloop, counted-vmcnt pipe -----
__device__ __forceinline__ void gemm64_mainloop(
    const unsigned short* __restrict__ Ag, const unsigned short* __restrict__ Bg,
    unsigned short* As, unsigned short* Bs, f32x4 acc[2][4]) {
  int t = threadIdx.x;
  int lane = t & 63, wid = t >> 6;
  int wm = (wid >> 1) * 32, wn = (wid & 1) * 64;
  int l15 = lane & 15, quad = lane >> 4;
  int srow = t >> 2, sko = (t & 3) * 8;
  const unsigned short* ga = Ag + (size_t)srow * 1024 + sko;
  const unsigned short* gb = Bg + (size_t)srow * 1024 + sko;
  unsigned short* la = As + t * 8;
  unsigned short* lb = Bs + t * 8;
#pragma unroll
  for (int mi = 0; mi < 2; ++mi)
#pragma unroll
    for (int j = 0; j < 4; ++j) acc[mi][j] = (f32x4){0.f, 0.f, 0.f, 0.f};

#define GO_STAGE(S, KT) do {                                               \
    int k0_ = (KT) * 32;                                                   \
    glds16(ga + k0_, la + (S) * 2048);                                     \
    glds16(gb + k0_, lb + (S) * 4096);                                     \
    glds16(gb + 64 * 1024 + k0_, lb + (S) * 4096 + 2048);                  \
  } while (0)

#define GO_COMP(S) do {                                                    \
    bf16x8 af[2], bfr[4];                                                  \
    _Pragma("unroll")                                                      \
    for (int mi = 0; mi < 2; ++mi)                                         \
      af[mi] = *(const bf16x8*)(As + (S) * 2048 + (wm + mi * 16 + l15) * 32 + quad * 8); \
    _Pragma("unroll")                                                      \
    for (int j = 0; j < 4; ++j)                                            \
      bfr[j] = *(const bf16x8*)(Bs + (S) * 4096 + (wn + j * 16 + l15) * 32 + quad * 8); \
    __builtin_amdgcn_s_setprio(1);                                         \
    _Pragma("unroll")                                                      \
    for (int mi = 0; mi < 2; ++mi)                                         \
      _Pragma("unroll")                                                    \
      for (int j = 0; j < 4; ++j)                                          \
        acc[mi][j] = __builtin_amdgcn_mfma_f32_16x16x32_bf16(af[mi], bfr[j], acc[mi][j], 0, 0, 0); \
    __builtin_amdgcn_s_setprio(0);                                         \
  } while (0)

  GO_STAGE(0, 0);
  GO_STAGE(1, 1);
  SYNC_VM(3);
  for (int kq = 0; kq < 32; kq += 4) {
    GO_STAGE(2, (kq + 2) & 31);
    GO_COMP(0);
    SYNC_VM(3);
    GO_STAGE(3, (kq + 3) & 31);
    GO_COMP(1);
    SYNC_VM(3);
    GO_STAGE(0, (kq + 4) & 31);   // wrap at end: harmless re-stage
    GO_COMP(2);
    SYNC_VM(3);
    GO_STAGE(1, (kq + 5) & 31);
    GO_COMP(3);
    SYNC_VM(3);
  }
  asm volatile("s_waitcnt vmcnt(0)" ::: "memory");
#undef GO_STAGE
#undef GO_COMP
}

// ------------- flash attention: 128 q-rows x 1 head per block --------------
// R13 fragment layout + counted-vmcnt pipeline. 1D grid 512, T1 chunked
// swizzle: swz = (bid%8)*64 + bid/8 -> each XCD owns 64 contiguous works =
// 2 full heads (their 1MB K/V L2-local across 32 blocks each).
__global__ __launch_bounds__(256, 2) void attn_kernel(
    const unsigned short* __restrict__ QB, const unsigned short* __restrict__ KB,
    const unsigned short* __restrict__ VT, unsigned short* __restrict__ AT) {
  __shared__ __align__(16) unsigned short Ks[4][4096];   // 4 slots x 64x64
  __shared__ __align__(16) unsigned short Vs[4][4096];
  int bid = blockIdx.x;
  int swz = (bid & 7) * 64 + (bid >> 3);        // bijective: 512 % 8 == 0
  int qt = swz & 31, h = swz >> 5;
  int hk = h & 3;                               // jnp.tile -> kv head = h % 4
  int t = threadIdx.x, lane = t & 63, w = t >> 6;
  int l15 = lane & 15, quad = lane >> 4;
  int qsel = w >> 1, ksel = w & 1;
  int q0 = qt * 128 + qsel * 64;                // wave's q rows: q0 + mi*16 + l15
  bf16x8 qf[4][2];
#pragma unroll
  for (int mi = 0; mi < 4; ++mi) {
    const unsigned short* qp = QB + ((size_t)h * NJ + q0 + mi * 16 + l15) * 64;
    qf[mi][0] = *(const bf16x8*)(qp + quad * 8);
    qf[mi][1] = *(const bf16x8*)(qp + 32 + quad * 8);
  }
  f32x4 oT[4][4];                               // O^T partial: [mi][db]
  f32x4 oL[4];                                  // ones-row accum (row0 = lsum)
#pragma unroll
  for (int mi = 0; mi < 4; ++mi) {
    oL[mi] = (f32x4){0.f, 0.f, 0.f, 0.f};
#pragma unroll
    for (int db = 0; db < 4; ++db) oT[mi][db] = (f32x4){0.f, 0.f, 0.f, 0.f};
  }
  bf16x8 vone;                                  // ones A-frag (row 0 only)
  {
    short one = (l15 == 0) ? (short)0x3F80 : (short)0;
    vone = (bf16x8){one, one, one, one, one, one, one, one};
  }
  const unsigned short* Kg = KB + (size_t)hk * NJ * 64;   // [key][d]
  const unsigned short* Vg = VT + (size_t)hk * 64 * NJ;   // [d][key]
  // ---- glds16 source addresses (per thread, loop-invariant) ----
  int r1 = t >> 3, cx = t & 7;
  int e1 = r1 & 7;
  int c1 = cx ^ e1;                             // swizzled 16B chunk
  int gk1 = 32 * (r1 >> 5) + 8 * ((r1 >> 2) & 3) + 4 * ((r1 >> 4) & 1) + (r1 & 3);
  int r2 = r1 + 32;
  int gk2 = 32 * (r2 >> 5) + 8 * ((r2 >> 2) & 3) + 4 * ((r2 >> 4) & 1) + (r2 & 3);
  const unsigned short* sK1 = Kg + (size_t)gk1 * 64 + c1 * 8;   // +tile*4096
  const unsigned short* sK2 = Kg + (size_t)gk2 * 64 + c1 * 8;
  const unsigned short* sV1 = Vg + (size_t)r1 * NJ + c1 * 8;    // +tile*64
  const unsigned short* sV2 = Vg + (size_t)r2 * NJ + c1 * 8;
  // ---- ds_read addresses (per lane, loop-invariant; + slot*4096 shorts) ----
  int e = l15 & 7;
  int co0 = (quad ^ e) * 8;                     // K lo chunk (d 0..31 quarter)
  int co1 = ((4 + quad) ^ e) * 8;               // K hi chunk
  int cov = (((ksel << 2) | quad) ^ e) * 8;     // V chunk (key half ksel)
  const unsigned short* kf0p = &Ks[0][(2 * ksel * 16 + l15) * 64] + co0;
  const unsigned short* kf0q = &Ks[0][(2 * ksel * 16 + l15) * 64] + co1;
  const unsigned short* kf1p = kf0p + 16 * 64;
  const unsigned short* kf1q = kf0q + 16 * 64;
  const unsigned short* vap0 = &Vs[0][(0 * 16 + l15) * 64] + cov;
  const unsigned short* vap1 = &Vs[0][(1 * 16 + l15) * 64] + cov;
  const unsigned short* vap2 = &Vs[0][(2 * 16 + l15) * 64] + cov;
  const unsigned short* vap3 = &Vs[0][(3 * 16 + l15) * 64] + cov;

  f32x4 sxA[4][2], sxB[4][2];
  bf16x8 pb[4];

#define STAGE(S, T) do {                                                   \
    size_t ko_ = (size_t)(T) * 4096;                                       \
    int vo_ = (T) * 64;                                                    \
    glds16(sK1 + ko_, &Ks[S][0] + t * 8);                                  \
    glds16(sK2 + ko_, &Ks[S][2048] + t * 8);                               \
    glds16(sV1 + vo_, &Vs[S][0] + t * 8);                                  \
    glds16(sV2 + vo_, &Vs[S][2048] + t * 8);                               \
  } while (0)

  // QK only (prologue): tile in slot S -> SX
#define QK4(S, SX) do {                                                    \
    bf16x8 k00 = *(const bf16x8*)(kf0p + (S) * 4096);                      \
    bf16x8 k01 = *(const bf16x8*)(kf0q + (S) * 4096);                      \
    bf16x8 k10 = *(const bf16x8*)(kf1p + (S) * 4096);                      \
    bf16x8 k11 = *(const bf16x8*)(kf1q + (S) * 4096);                      \
    _Pragma("unroll")                                                      \
    for (int mi = 0; mi < 4; ++mi) {                                       \
      f32x4 z0 = (f32x4){0.f, 0.f, 0.f, 0.f};                              \
      z0 = __builtin_amdgcn_mfma_f32_16x16x32_bf16(k00, qf[mi][0], z0, 0, 0, 0); \
      z0 = __builtin_amdgcn_mfma_f32_16x16x32_bf16(k01, qf[mi][1], z0, 0, 0, 0); \
      (SX)[mi][0] = z0;                                                    \
      f32x4 z1 = (f32x4){0.f, 0.f, 0.f, 0.f};                              \
      z1 = __builtin_amdgcn_mfma_f32_16x16x32_bf16(k10, qf[mi][0], z1, 0, 0, 0); \
      z1 = __builtin_amdgcn_mfma_f32_16x16x32_bf16(k11, qf[mi][1], z1, 0, 0, 0); \
      (SX)[mi][1] = z1;                                                    \
    }                                                                      \
  } while (0)

  // interleaved: QK(next tile, slot SQ) -> SXN while exp(SXP) -> pb
#define PHASE_A(SQ, SXN, SXP) do {                                         \
    bf16x8 k00 = *(const bf16x8*)(kf0p + (SQ) * 4096);                     \
    bf16x8 k01 = *(const bf16x8*)(kf0q + (SQ) * 4096);                     \
    bf16x8 k10 = *(const bf16x8*)(kf1p + (SQ) * 4096);                     \
    bf16x8 k11 = *(const bf16x8*)(kf1q + (SQ) * 4096);                     \
    _Pragma("unroll")                                                      \
    for (int mi = 0; mi < 4; ++mi) {                                       \
      f32x4 z0 = (f32x4){0.f, 0.f, 0.f, 0.f};                              \
      z0 = __builtin_amdgcn_mfma_f32_16x16x32_bf16(k00, qf[mi][0], z0, 0, 0, 0); \
      z0 = __builtin_amdgcn_mfma_f32_16x16x32_bf16(k01, qf[mi][1], z0, 0, 0, 0); \
      (SXN)[mi][0] = z0;                                                   \
      f32x4 z1 = (f32x4){0.f, 0.f, 0.f, 0.f};                              \
      z1 = __builtin_amdgcn_mfma_f32_16x16x32_bf16(k10, qf[mi][0], z1, 0, 0, 0); \
      z1 = __builtin_amdgcn_mfma_f32_16x16x32_bf16(k11, qf[mi][1], z1, 0, 0, 0); \
      (SXN)[mi][1] = z1;                                                   \
      union { bf16x8 v; uint32_t u[4]; } pk_;                              \
      pk_.u[0] = pack2bf(FAST_EXP2((SXP)[mi][0][0]), FAST_EXP2((SXP)[mi][0][1])); \
      pk_.u[1] = pack2bf(FAST_EXP2((SXP)[mi][0][2]), FAST_EXP2((SXP)[mi][0][3])); \
      pk_.u[2] = pack2bf(FAST_EXP2((SXP)[mi][1][0]), FAST_EXP2((SXP)[mi][1][1])); \
      pk_.u[3] = pack2bf(FAST_EXP2((SXP)[mi][1][2]), FAST_EXP2((SXP)[mi][1][3])); \
      pb[mi] = pk_.v;                                                      \
    }                                                                      \
  } while (0)

#define PHASE_B(SP) do {                                                   \
    __builtin_amdgcn_s_setprio(1);                                         \
    {                                                                      \
      bf16x8 va0 = *(const bf16x8*)(vap0 + (SP) * 4096);                   \
      bf16x8 va1 = *(const bf16x8*)(vap1 + (SP) * 4096);                   \
      bf16x8 va2 = *(const bf16x8*)(vap2 + (SP) * 4096);                   \
      bf16x8 va3 = *(const bf16x8*)(vap3 + (SP) * 4096);                   \
      _Pragma("unroll")                                                    \
      for (int mi = 0; mi < 4; ++mi) {                                     \
        oT[mi][0] = __builtin_amdgcn_mfma_f32_16x16x32_bf16(va0, pb[mi], oT[mi][0], 0, 0, 0); \
        oT[mi][1] = __builtin_amdgcn_mfma_f32_16x16x32_bf16(va1, pb[mi], oT[mi][1], 0, 0, 0); \
        oT[mi][2] = __builtin_amdgcn_mfma_f32_16x16x32_bf16(va2, pb[mi], oT[mi][2], 0, 0, 0); \
        oT[mi][3] = __builtin_amdgcn_mfma_f32_16x16x32_bf16(va3, pb[mi], oT[mi][3], 0, 0, 0); \
        oL[mi] = __builtin_amdgcn_mfma_f32_16x16x32_bf16(vone, pb[mi], oL[mi], 0, 0, 0); \
      }                                                                    \
    }                                                                      \
    __builtin_amdgcn_s_setprio(0);                                         \
  } while (0)

  // prologue: stage tiles 0,1,2; retire 0,1 (leave 2 flying); QK(0) -> sxA
  STAGE(0, 0);
  STAGE(1, 1);
  STAGE(2, 2);
  SYNC_VM(4);
  QK4(0, sxA);
  for (int P = 0; P < 16; ++P) {
    int tb = 4 * P;
    // half 1: PV(tb)@s0, QK(tb+1)@s1 || exp(tb), stage(tb+3)->s3
    STAGE(3, (tb + 3) & 63);
    PHASE_A(1, sxB, sxA);
    PHASE_B(0);
    SYNC_VM(4);
    // half 2: PV(tb+1)@s1, QK(tb+2)@s2 || exp(tb+1), stage(tb+4)->s0
    STAGE(0, (tb + 4) & 63);
    PHASE_A(2, sxA, sxB);
    PHASE_B(1);
    SYNC_VM(4);
    // half 3: PV(tb+2)@s2, QK(tb+3)@s3 || exp(tb+2), stage(tb+5)->s1
    STAGE(1, (tb + 5) & 63);
    PHASE_A(3, sxB, sxA);
    PHASE_B(2);
    SYNC_VM(4);
    // half 4: PV(tb+3)@s3, QK(tb+4)@s0 || exp(tb+3), stage(tb+6)->s2
    STAGE(2, (tb + 6) & 63);
    PHASE_A(0, sxA, sxB);
    PHASE_B(3);
    SYNC_VM(4);
  }
  // full drain before reusing LDS as combine scratch (in-flight glds16
  // would stomp it)
  __syncthreads();
#undef STAGE
#undef QK4
#undef PHASE_A
#undef PHASE_B

  // ---- combine key-split partials across wave pairs (ksel 0 <- 1) ----
  float ls[4];
#pragma unroll
  for (int mi = 0; mi < 4; ++mi) {
    float s = oL[mi][0];
    s += __shfl_xor(s, 16, 64);
    s += __shfl_xor(s, 32, 64);
    ls[mi] = s;
  }
  // per-qsel scratch: qsel0 -> Ks region (32 KB), qsel1 -> Vs region.
  // oT at lane stride 17 f32x4 (272 B); ls after (offset 64*68 floats).
  float* xb = (qsel == 0) ? (float*)&Ks[0][0] : (float*)&Vs[0][0];
  float* xl = xb + 64 * 68;
  if (ksel == 1) {
    f32x4* dst = (f32x4*)xb + (size_t)lane * 17;
#pragma unroll
    for (int mi = 0; mi < 4; ++mi)
#pragma unroll
      for (int db = 0; db < 4; ++db) dst[mi * 4 + db] = oT[mi][db];
    float* dl = xl + lane * 4;
#pragma unroll
    for (int mi = 0; mi < 4; ++mi) dl[mi] = ls[mi];
  }
  __syncthreads();
  if (ksel == 0) {
    const f32x4* src = (const f32x4*)xb + (size_t)lane * 17;
    const float* sl = xl + lane * 4;
#pragma unroll
    for (int mi = 0; mi < 4; ++mi) {
      float inv = 1.0f / (ls[mi] + sl[mi]);
      int qrow = q0 + mi * 16 + l15;
#pragma unroll
      for (int db = 0; db < 4; ++db) {
        f32x4 o = oT[mi][db] + src[mi * 4 + db];
        union { bf16x4 v; uint32_t u[2]; } ov;
        ov.u[0] = pack2bf(o[0] * inv, o[1] * inv);
        ov.u[1] = pack2bf(o[2] * inv, o[3] * inv);
        *(bf16x4*)(AT + (size_t)qrow * DIMM + h * 64 + db * 16 + quad * 4) = ov.v;
      }
    }
  }
}

// ---------------- output GEMM: AT (4096x1024) @ Wout^T + bias -> f32 -------
// 1D grid 512, T1 chunked swizzle: each XCD owns 64 contiguous works =
// 8 m-rows x 8 n (A-panels L2-local, 8x reuse).
__global__ __launch_bounds__(256) void gemm_out_kernel(
    const unsigned short* __restrict__ AT, const unsigned short* __restrict__ WOT,
    const float* __restrict__ ba, const float* __restrict__ bx,
    float* __restrict__ out) {
  __shared__ unsigned short As[4 * 2048], Bs[4 * 4096];   // 48 KB
  int bid = blockIdx.x;
  int swz = (bid & 7) * 64 + (bid >> 3);        // bijective: 512 % 8 == 0
  int n0 = (swz & 7) * 128, m0 = (swz >> 3) * 64;
  int s = (m0 >= 2048) ? 1 : 0;                 // 0 = a-stream rows, 1 = x
  const unsigned short* Ag = AT + (size_t)m0 * 1024;
  const unsigned short* Bg = WOT + (size_t)s * 1024 * 1024 + (size_t)n0 * 1024;
  f32x4 acc[2][4];
  gemm64_mainloop(Ag, Bg, As, Bs, acc);
  int t = threadIdx.x, lane = t & 63, wid = t >> 6;
  int wm = (wid >> 1) * 32, wn = (wid & 1) * 64;
  int l15 = lane & 15, quad = lane >> 4;
  const float* bias = s ? bx : ba;
  // d_out = [out_x (2048x1024) | out_a (2048x1024)]
  float* obase = s ? (out + (size_t)(m0 - 2048) * 1024)
                   : (out + (size_t)2048 * 1024 + (size_t)m0 * 1024);
#pragma unroll
  for (int mi = 0; mi < 2; ++mi)
#pragma unroll
    for (int r = 0; r < 4; ++r) {
      int row = wm + mi * 16 + quad * 4 + r;
#pragma unroll
      for (int j = 0; j < 4; ++j) {
        int col = n0 + wn + j * 16 + l15;
        obase[(size_t)row * 1024 + col] = acc[mi][j][r] + bias[col];
      }
    }
}

// ---------------------------------------------------------------------------
extern "C" void kernel_launch(void* const* d_in, const int* in_sizes, int n_in,
                              void* d_out, int out_size, void* d_ws, size_t ws_size,
                              hipStream_t stream) {
  const float* x      = (const float*)d_in[0];
  const float* a      = (const float*)d_in[1];
  const float* g_x    = (const float*)d_in[2];
  const float* g_a    = (const float*)d_in[3];
  const float* Wq_x   = (const float*)d_in[4];
  const float* Wkv_x  = (const float*)d_in[5];
  const float* Wq_a   = (const float*)d_in[6];
  const float* Wkv_a  = (const float*)d_in[7];
  const float* Wout_x = (const float*)d_in[8];
  const float* bout_x = (const float*)d_in[9];
  const float* Wout_a = (const float*)d_in[10];
  const float* bout_a = (const float*)d_in[11];
  float* out = (float*)d_out;

  // workspace (30 MB). AT aliases XN (dead after gemm_qkv).
  char* ws = (char*)d_ws;
  const size_t MB = 1024 * 1024;
  unsigned short* XN   = (unsigned short*)(ws);            // 8 MB
  unsigned short* WQT  = (unsigned short*)(ws + 8 * MB);   // 4 MB
  unsigned short* WKVT = (unsigned short*)(ws + 12 * MB);  // 2 MB
  unsigned short* WOT  = (unsigned short*)(ws + 14 * MB);  // 4 MB
  unsigned short* QB   = (unsigned short*)(ws + 18 * MB);  // 8 MB
  unsigned short* KB   = (unsigned short*)(ws + 26 * MB);  // 2 MB
  unsigned short* VT   = (unsigned short*)(ws + 28 * MB);  // 2 MB
  unsigned short* AT   = XN;                               // alias

  prep_kernel<<<dim3(10240), dim3(256), 0, stream>>>(
      a, x, g_a, g_x, Wq_a, Wq_x, Wkv_a, Wkv_x, Wout_a, Wout_x,
      XN, WQT, WKVT, WOT);
  gemm_qkv_kernel<<<dim3(384), dim3(256), 0, stream>>>(
      XN, WQT, WKVT, QB, KB, VT);
  attn_kernel<<<dim3(512), dim3(256), 0, stream>>>(QB, KB, VT, AT);
  gemm_out_kernel<<<dim3(512), dim3(256), 0, stream>>>(
      AT, WOT, bout_a, bout_x, out);
}

// Round 13
// 214.261 us; speedup vs baseline: 1.0436x; 1.0056x over previous
//
#include <hip/hip_runtime.h>
#include <hip/hip_bf16.h>
#include <stdint.h>
#include <math.h>

// ---------------------------------------------------------------------------
// JointAttention: dual-stream rmsnorm -> QKV proj -> RoPE -> joint attention
// over concat(a, x) (4096 tokens, 16 q-heads, 4 kv-heads tiled h%4) -> out proj.
// All matmuls in bf16 MFMA, fp32 accumulate.
//
// R21 = R20 (best, 215.5us) with gemm_qkv moved to BM=64 for TLP:
//  - The one untested GEMM combination: small-BM (high TLP) WITH the
//    counted-vmcnt slot pipeline + T1 + T5. qkv was 384 blocks = 1.5/CU
//    (half the CUs idle in its tail); at BM=64 it is 768 blocks = 3/CU
//    (48 KB LDS). Staging traffic rises 192->288 MB (~+3us of L2 reads),
//    TLP doubles. K=1024 short-K GEMMs are latency-dominated -> TLP wins
//    if anything does. 7th structural probe; null => GEMM floor proven.
//  - qkv reuses the shared gemm64 mainloop (T5'd); epilogue is R12's
//    verified BM=64 RoPE/V layout with R17's inline trig.
//  - attn / gemm_out / prep byte-identical to R20.
// ---------------------------------------------------------------------------

#define NSEQ 2048
#define NJ   4096
#define DIMM 1024

typedef __attribute__((ext_vector_type(4))) float f32x4;
typedef __attribute__((ext_vector_type(8))) short bf16x8;
typedef __attribute__((ext_vector_type(4))) short bf16x4;

__device__ __forceinline__ unsigned short f2bf(float f) {
  union { float f; uint32_t u; } v; v.f = f;
  return (unsigned short)((v.u + 0x7FFFu + ((v.u >> 16) & 1u)) >> 16);
}

__device__ __forceinline__ uint32_t pack2bf(float a, float b) {
  __hip_bfloat162 h = __float22bfloat162_rn(float2{a, b});
  union { __hip_bfloat162 h; uint32_t u; } c; c.h = h;
  return c.u;
}

#if defined(__has_builtin)
#if __has_builtin(__builtin_amdgcn_exp2f)
#define FAST_EXP2(x) __builtin_amdgcn_exp2f(x)
#endif
#endif
#ifndef FAST_EXP2
#define FAST_EXP2(x) exp2f(x)
#endif

// async global->LDS, 16B per lane; LDS dest = wave-uniform base + lane*16
__device__ __forceinline__ void glds16(const void* g, void* l) {
  __builtin_amdgcn_global_load_lds(
      (const __attribute__((address_space(1))) unsigned int*)g,
      (__attribute__((address_space(3))) unsigned int*)l, 16, 0, 0);
}

// counted-vmcnt barrier: retire all but the newest N vmem ops, then barrier.
#define SYNC_VM(N) do {                                                    \
    asm volatile("s_waitcnt vmcnt(" #N ")" ::: "memory");                  \
    __builtin_amdgcn_sched_barrier(0);                                     \
    __builtin_amdgcn_s_barrier();                                          \
    __builtin_amdgcn_sched_barrier(0);                                     \
  } while (0)

// rope trig: cos/sin(2*pos * 10^(-i/8)) via f64 binexp + native f32 trig
__device__ __forceinline__ void rope_cs(int pos, int i, float* c, float* s) {
  double inv = 1.0;
  if (i & 1)  inv *= 0.74989420933245582;     // 10^(-1/8)
  if (i & 2)  inv *= 0.56234132519034908;     // 10^(-1/4)
  if (i & 4)  inv *= 0.31622776601683794;     // 10^(-1/2)
  if (i & 8)  inv *= 0.1;
  if (i & 16) inv *= 0.01;
  double rev = (double)(2 * pos) * inv * 0.15915494309189535;
  rev -= floor(rev);
  float rf = (float)rev;
  float cc, ss;
  asm("v_cos_f32 %0, %1" : "=v"(cc) : "v"(rf));  // D = cos(S0*2pi)
  asm("v_sin_f32 %0, %1" : "=v"(ss) : "v"(rf));  // D = sin(S0*2pi)
  *c = cc; *s = ss;
}

// ---------------- fused prep: weight cast+transpose + rmsnorm --------------
// flat grid: [0,6144) transpose f32[1024][N] -> bf16[N][1024];
//            [6144,10240) rmsnorm + bf16 cast
__global__ __launch_bounds__(256) void prep_kernel(
    const float* __restrict__ xa, const float* __restrict__ xx,
    const float* __restrict__ ga, const float* __restrict__ gx,
    const float* __restrict__ wqa, const float* __restrict__ wqx,
    const float* __restrict__ wkva, const float* __restrict__ wkvx,
    const float* __restrict__ woa, const float* __restrict__ wox,
    unsigned short* __restrict__ XN, unsigned short* __restrict__ WQT,
    unsigned short* __restrict__ WKVT, unsigned short* __restrict__ WOT) {
  __shared__ float tile[32][33];
  __shared__ float red[4];
  int bid = blockIdx.x, t = threadIdx.x;
  if (bid < 6144) {
    int b = bid;
    int z = b >> 10, yx = b & 1023;
    int n0 = (yx >> 5) * 32, k0 = (yx & 31) * 32;
    int s = z & 1, ty = z >> 1;
    int N = (ty == 1) ? 512 : 1024;
    if (n0 >= N) return;                        // block-uniform
    const float* src = (z == 0) ? wqa : (z == 1) ? wqx : (z == 2) ? wkva
                     : (z == 3) ? wkvx : (z == 4) ? woa : wox;
    unsigned short* dst = (ty == 0) ? WQT + (size_t)s * 1024 * 1024
                        : (ty == 1) ? WKVT + (size_t)s * 512 * 1024
                                    : WOT + (size_t)s * 1024 * 1024;
    int r = t >> 3, c4 = (t & 7) * 4;
    f32x4 v = *(const f32x4*)(src + (size_t)(k0 + r) * N + n0 + c4);
    tile[r][c4 + 0] = v.x; tile[r][c4 + 1] = v.y;
    tile[r][c4 + 2] = v.z; tile[r][c4 + 3] = v.w;
    __syncthreads();
    int nn = t >> 3, kk = (t & 7) * 4;
    bf16x4 o;
    o.x = (short)f2bf(tile[kk + 0][nn]);
    o.y = (short)f2bf(tile[kk + 1][nn]);
    o.z = (short)f2bf(tile[kk + 2][nn]);
    o.w = (short)f2bf(tile[kk + 3][nn]);
    *(bf16x4*)(dst + (size_t)(n0 + nn) * 1024 + k0 + kk) = o;
  } else {
    int b = bid - 6144;
    int s = b >> 11, row = b & 2047;
    const float* src = (s == 0 ? xa : xx) + (size_t)row * DIMM;
    const float* g = (s == 0 ? ga : gx);
    f32x4 v = *(const f32x4*)(src + t * 4);
    float ss = v.x * v.x + v.y * v.y + v.z * v.z + v.w * v.w;
#pragma unroll
    for (int o = 32; o > 0; o >>= 1) ss += __shfl_xor(ss, o, 64);
    if ((t & 63) == 0) red[t >> 6] = ss;
    __syncthreads();
    float tot = red[0] + red[1] + red[2] + red[3];
    float rs = rsqrtf(tot * (1.0f / DIMM) + 1e-6f);
    f32x4 gv = *(const f32x4*)(g + t * 4);
    bf16x4 o;
    o.x = (short)f2bf(v.x * rs * gv.x);
    o.y = (short)f2bf(v.y * rs * gv.y);
    o.z = (short)f2bf(v.z * rs * gv.z);
    o.w = (short)f2bf(v.w * rs * gv.w);
    *(bf16x4*)(XN + ((size_t)s * NSEQ + row) * DIMM + t * 4) = o;
  }
}

// ---- shared 64x128x(K=1024) bf16 NT GEMM mainloop, counted-vmcnt pipe -----
// A slot 64x32 (2048 sh), B slot 128x32 (4096 sh); 4 slots each (48 KB).
// Step k: stage slot (k+2)&3, compute slot k&3, vmcnt(3)+barrier. T5'd.
__device__ __forceinline__ void gemm64_mainloop(
    const unsigned short* __restrict__ Ag, const unsigned short* __restrict__ Bg,
    unsigned short* As, unsigned short* Bs, f32x4 acc[2][4]) {
  int t = threadIdx.x;
  int lane = t & 63, wid = t >> 6;
  int wm = (wid >> 1) * 32, wn = (wid & 1) * 64;
  int l15 = lane & 15, quad = lane >> 4;
  int srow = t >> 2, sko = (t & 3) * 8;
  const unsigned short* ga = Ag + (size_t)srow * 1024 + sko;
  const unsigned short* gb = Bg + (size_t)srow * 1024 + sko;
  unsigned short* la = As + t * 8;
  unsigned short* lb = Bs + t * 8;
#pragma unroll
  for (int mi = 0; mi < 2; ++mi)
#pragma unroll
    for (int j = 0; j < 4; ++j) acc[mi][j] = (f32x4){0.f, 0.f, 0.f, 0.f};

#define GO_STAGE(S, KT) do {                                               \
    int k0_ = (KT) * 32;                                                   \
    glds16(ga + k0_, la + (S) * 2048);                                     \
    glds16(gb + k0_, lb + (S) * 4096);                                     \
    glds16(gb + 64 * 1024 + k0_, lb + (S) * 4096 + 2048);                  \
  } while (0)

#define GO_COMP(S) do {                                                    \
    bf16x8 af[2], bfr[4];                                                  \
    _Pragma("unroll")                                                      \
    for (int mi = 0; mi < 2; ++mi)                                         \
      af[mi] = *(const bf16x8*)(As + (S) * 2048 + (wm + mi * 16 + l15) * 32 + quad * 8); \
    _Pragma("unroll")                                                      \
    for (int j = 0; j < 4; ++j)                                            \
      bfr[j] = *(const bf16x8*)(Bs + (S) * 4096 + (wn + j * 16 + l15) * 32 + quad * 8); \
    __builtin_amdgcn_s_setprio(1);                                         \
    _Pragma("unroll")                                                      \
    for (int mi = 0; mi < 2; ++mi)                                         \
      _Pragma("unroll")                                                    \
      for (int j = 0; j < 4; ++j)                                          \
        acc[mi][j] = __builtin_amdgcn_mfma_f32_16x16x32_bf16(af[mi], bfr[j], acc[mi][j], 0, 0, 0); \
    __builtin_amdgcn_s_setprio(0);                                         \
  } while (0)

  GO_STAGE(0, 0);
  GO_STAGE(1, 1);
  SYNC_VM(3);
  for (int kq = 0; kq < 32; kq += 4) {
    GO_STAGE(2, (kq + 2) & 31);
    GO_COMP(0);
    SYNC_VM(3);
    GO_STAGE(3, (kq + 3) & 31);
    GO_COMP(1);
    SYNC_VM(3);
    GO_STAGE(0, (kq + 4) & 31);   // wrap at end: harmless re-stage
    GO_COMP(2);
    SYNC_VM(3);
    GO_STAGE(1, (kq + 5) & 31);
    GO_COMP(3);
    SYNC_VM(3);
  }
  asm volatile("s_waitcnt vmcnt(0)" ::: "memory");
#undef GO_STAGE
#undef GO_COMP
}

// ------ QKV GEMM: BM=64 (TLP) + counted-vmcnt 4-slot pipe + T1 + T5 --------
// A=[an;xn] (4096x1024), N=1536 (Q 1024 | K 256 | V 256). 1D grid 768
// (12 n x 64 m), T1 chunk 96: each XCD owns 8 m-rows x 12 n (A-panels
// L2-local). 48 KB LDS -> 3 blocks/CU. Epilogue: RoPE inline trig (R12's
// verified BM=64 layout); q carries scales+log2(e); V written transposed.
__global__ __launch_bounds__(256) void gemm_qkv_kernel(
    const unsigned short* __restrict__ XN, const unsigned short* __restrict__ WQT,
    const unsigned short* __restrict__ WKVT, unsigned short* __restrict__ QB,
    unsigned short* __restrict__ KB, unsigned short* __restrict__ VT) {
  __shared__ unsigned short As[4 * 2048], Bs[4 * 4096];   // 48 KB
  int bid = blockIdx.x;
  int swz = (bid & 7) * 96 + (bid >> 3);        // bijective: 768 % 8 == 0
  int n0 = (swz % 12) * 128, m0 = (swz / 12) * 64;
  int s = (m0 >= 2048) ? 1 : 0;
  const unsigned short* Ag = XN + (size_t)m0 * 1024;
  const unsigned short* Bg = (n0 < 1024)
      ? WQT + (size_t)s * 1024 * 1024 + (size_t)n0 * 1024
      : WKVT + (size_t)s * 512 * 1024 + (size_t)(n0 - 1024) * 1024;
  f32x4 acc[2][4];
  gemm64_mainloop(Ag, Bg, As, Bs, acc);
  int t = threadIdx.x, lane = t & 63, wid = t >> 6;
  int wm = (wid >> 1) * 32, wn = (wid & 1) * 64;
  int l15 = lane & 15, quad = lane >> 4;
  int coln = n0 + wn;                     // 64-aligned -> head-uniform per wave
  if (coln < 1280) {
    bool isq = coln < 1024;
    float sc = isq ? (1.4426950408889634f / 64.0f) : 1.0f;  // 1/64 * log2(e)
    unsigned short* dstBase;
    if (isq) dstBase = QB + (size_t)(coln >> 6) * NJ * 64;
    else     dstBase = KB + (size_t)((coln - 1024) >> 6) * NJ * 64;
#pragma unroll
    for (int mi = 0; mi < 2; ++mi)
#pragma unroll
      for (int r = 0; r < 4; ++r) {
        int jr = m0 + wm + mi * 16 + quad * 4 + r;   // joint row (a:0..2047, x:2048..)
        int pos = jr & 2047;
#pragma unroll
        for (int jp = 0; jp < 2; ++jp) {             // d = jp*16+l15 pairs with d+32
          int i = jp * 16 + l15;
          float c, sn;
          rope_cs(pos, i, &c, &sn);
          float x1 = acc[mi][jp][r], x2 = acc[mi][jp + 2][r];
          dstBase[(size_t)jr * 64 + jp * 16 + l15]      = f2bf((x1 * c - x2 * sn) * sc);
          dstBase[(size_t)jr * 64 + 32 + jp * 16 + l15] = f2bf((x2 * c + x1 * sn) * sc);
        }
      }
  } else {
    // V: write straight to VT[d][jr] -- acc[mi][j][0..3] are 4 consecutive jr
    int cvb = coln - 1280;
#pragma unroll
    for (int mi = 0; mi < 2; ++mi)
#pragma unroll
      for (int j = 0; j < 4; ++j) {
        int d = cvb + j * 16 + l15;                  // 0..255 = hk*64 + dh
        int jr0 = m0 + wm + mi * 16 + quad * 4;
        union { bf16x4 v; uint32_t u[2]; } pv;
        pv.u[0] = pack2bf(acc[mi][j][0], acc[mi][j][1]);
        pv.u[1] = pack2bf(acc[mi][j][2], acc[mi][j][3]);
        *(bf16x4*)(VT + (size_t)d * NJ + jr0) = pv.v;
      }
  }
}

// ------------- flash attention: 128 q-rows x 1 head per block --------------
// R13 fragment layout + counted-vmcnt pipeline. 1D grid 512, T1 chunked
// swizzle: swz = (bid%8)*64 + bid/8 -> each XCD owns 64 contiguous works =
// 2 full heads (their 1MB K/V L2-local across 32 blocks each).
__global__ __launch_bounds__(256, 2) void attn_kernel(
    const unsigned short* __restrict__ QB, const unsigned short* __restrict__ KB,
    const unsigned short* __restrict__ VT, unsigned short* __restrict__ AT) {
  __shared__ __align__(16) unsigned short Ks[4][4096];   // 4 slots x 64x64
  __shared__ __align__(16) unsigned short Vs[4][4096];
  int bid = blockIdx.x;
  int swz = (bid & 7) * 64 + (bid >> 3);        // bijective: 512 % 8 == 0
  int qt = swz & 31, h = swz >> 5;
  int hk = h & 3;                               // jnp.tile -> kv head = h % 4
  int t = threadIdx.x, lane = t & 63, w = t >> 6;
  int l15 = lane & 15, quad = lane >> 4;
  int qsel = w >> 1, ksel = w & 1;
  int q0 = qt * 128 + qsel * 64;                // wave's q rows: q0 + mi*16 + l15
  bf16x8 qf[4][2];
#pragma unroll
  for (int mi = 0; mi < 4; ++mi) {
    const unsigned short* qp = QB + ((size_t)h * NJ + q0 + mi * 16 + l15) * 64;
    qf[mi][0] = *(const bf16x8*)(qp + quad * 8);
    qf[mi][1] = *(const bf16x8*)(qp + 32 + quad * 8);
  }
  f32x4 oT[4][4];                               // O^T partial: [mi][db]
  f32x4 oL[4];                                  // ones-row accum (row0 = lsum)
#pragma unroll
  for (int mi = 0; mi < 4; ++mi) {
    oL[mi] = (f32x4){0.f, 0.f, 0.f, 0.f};
#pragma unroll
    for (int db = 0; db < 4; ++db) oT[mi][db] = (f32x4){0.f, 0.f, 0.f, 0.f};
  }
  bf16x8 vone;                                  // ones A-frag (row 0 only)
  {
    short one = (l15 == 0) ? (short)0x3F80 : (short)0;
    vone = (bf16x8){one, one, one, one, one, one, one, one};
  }
  const unsigned short* Kg = KB + (size_t)hk * NJ * 64;   // [key][d]
  const unsigned short* Vg = VT + (size_t)hk * 64 * NJ;   // [d][key]
  // ---- glds16 source addresses (per thread, loop-invariant) ----
  int r1 = t >> 3, cx = t & 7;
  int e1 = r1 & 7;
  int c1 = cx ^ e1;                             // swizzled 16B chunk
  int gk1 = 32 * (r1 >> 5) + 8 * ((r1 >> 2) & 3) + 4 * ((r1 >> 4) & 1) + (r1 & 3);
  int r2 = r1 + 32;
  int gk2 = 32 * (r2 >> 5) + 8 * ((r2 >> 2) & 3) + 4 * ((r2 >> 4) & 1) + (r2 & 3);
  const unsigned short* sK1 = Kg + (size_t)gk1 * 64 + c1 * 8;   // +tile*4096
  const unsigned short* sK2 = Kg + (size_t)gk2 * 64 + c1 * 8;
  const unsigned short* sV1 = Vg + (size_t)r1 * NJ + c1 * 8;    // +tile*64
  const unsigned short* sV2 = Vg + (size_t)r2 * NJ + c1 * 8;
  // ---- ds_read addresses (per lane, loop-invariant; + slot*4096 shorts) ----
  int e = l15 & 7;
  int co0 = (quad ^ e) * 8;                     // K lo chunk (d 0..31 quarter)
  int co1 = ((4 + quad) ^ e) * 8;               // K hi chunk
  int cov = (((ksel << 2) | quad) ^ e) * 8;     // V chunk (key half ksel)
  const unsigned short* kf0p = &Ks[0][(2 * ksel * 16 + l15) * 64] + co0;
  const unsigned short* kf0q = &Ks[0][(2 * ksel * 16 + l15) * 64] + co1;
  const unsigned short* kf1p = kf0p + 16 * 64;
  const unsigned short* kf1q = kf0q + 16 * 64;
  const unsigned short* vap0 = &Vs[0][(0 * 16 + l15) * 64] + cov;
  const unsigned short* vap1 = &Vs[0][(1 * 16 + l15) * 64] + cov;
  const unsigned short* vap2 = &Vs[0][(2 * 16 + l15) * 64] + cov;
  const unsigned short* vap3 = &Vs[0][(3 * 16 + l15) * 64] + cov;

  f32x4 sxA[4][2], sxB[4][2];
  bf16x8 pb[4];

#define STAGE(S, T) do {                                                   \
    size_t ko_ = (size_t)(T) * 4096;                                       \
    int vo_ = (T) * 64;                                                    \
    glds16(sK1 + ko_, &Ks[S][0] + t * 8);                                  \
    glds16(sK2 + ko_, &Ks[S][2048] + t * 8);                               \
    glds16(sV1 + vo_, &Vs[S][0] + t * 8);                                  \
    glds16(sV2 + vo_, &Vs[S][2048] + t * 8);                               \
  } while (0)

  // QK only (prologue): tile in slot S -> SX
#define QK4(S, SX) do {                                                    \
    bf16x8 k00 = *(const bf16x8*)(kf0p + (S) * 4096);                      \
    bf16x8 k01 = *(const bf16x8*)(kf0q + (S) * 4096);                      \
    bf16x8 k10 = *(const bf16x8*)(kf1p + (S) * 4096);                      \
    bf16x8 k11 = *(const bf16x8*)(kf1q + (S) * 4096);                      \
    _Pragma("unroll")                                                      \
    for (int mi = 0; mi < 4; ++mi) {                                       \
      f32x4 z0 = (f32x4){0.f, 0.f, 0.f, 0.f};                              \
      z0 = __builtin_amdgcn_mfma_f32_16x16x32_bf16(k00, qf[mi][0], z0, 0, 0, 0); \
      z0 = __builtin_amdgcn_mfma_f32_16x16x32_bf16(k01, qf[mi][1], z0, 0, 0, 0); \
      (SX)[mi][0] = z0;                                                    \
      f32x4 z1 = (f32x4){0.f, 0.f, 0.f, 0.f};                              \
      z1 = __builtin_amdgcn_mfma_f32_16x16x32_bf16(k10, qf[mi][0], z1, 0, 0, 0); \
      z1 = __builtin_amdgcn_mfma_f32_16x16x32_bf16(k11, qf[mi][1], z1, 0, 0, 0); \
      (SX)[mi][1] = z1;                                                    \
    }                                                                      \
  } while (0)

  // interleaved: QK(next tile, slot SQ) -> SXN while exp(SXP) -> pb
#define PHASE_A(SQ, SXN, SXP) do {                                         \
    bf16x8 k00 = *(const bf16x8*)(kf0p + (SQ) * 4096);                     \
    bf16x8 k01 = *(const bf16x8*)(kf0q + (SQ) * 4096);                     \
    bf16x8 k10 = *(const bf16x8*)(kf1p + (SQ) * 4096);                     \
    bf16x8 k11 = *(const bf16x8*)(kf1q + (SQ) * 4096);                     \
    _Pragma("unroll")                                                      \
    for (int mi = 0; mi < 4; ++mi) {                                       \
      f32x4 z0 = (f32x4){0.f, 0.f, 0.f, 0.f};                              \
      z0 = __builtin_amdgcn_mfma_f32_16x16x32_bf16(k00, qf[mi][0], z0, 0, 0, 0); \
      z0 = __builtin_amdgcn_mfma_f32_16x16x32_bf16(k01, qf[mi][1], z0, 0, 0, 0); \
      (SXN)[mi][0] = z0;                                                   \
      f32x4 z1 = (f32x4){0.f, 0.f, 0.f, 0.f};                              \
      z1 = __builtin_amdgcn_mfma_f32_16x16x32_bf16(k10, qf[mi][0], z1, 0, 0, 0); \
      z1 = __builtin_amdgcn_mfma_f32_16x16x32_bf16(k11, qf[mi][1], z1, 0, 0, 0); \
      (SXN)[mi][1] = z1;                                                   \
      union { bf16x8 v; uint32_t u[4]; } pk_;                              \
      pk_.u[0] = pack2bf(FAST_EXP2((SXP)[mi][0][0]), FAST_EXP2((SXP)[mi][0][1])); \
      pk_.u[1] = pack2bf(FAST_EXP2((SXP)[mi][0][2]), FAST_EXP2((SXP)[mi][0][3])); \
      pk_.u[2] = pack2bf(FAST_EXP2((SXP)[mi][1][0]), FAST_EXP2((SXP)[mi][1][1])); \
      pk_.u[3] = pack2bf(FAST_EXP2((SXP)[mi][1][2]), FAST_EXP2((SXP)[mi][1][3])); \
      pb[mi] = pk_.v;                                                      \
    }                                                                      \
  } while (0)

#define PHASE_B(SP) do {                                                   \
    __builtin_amdgcn_s_setprio(1);                                         \
    {                                                                      \
      bf16x8 va0 = *(const bf16x8*)(vap0 + (SP) * 4096);                   \
      bf16x8 va1 = *(const bf16x8*)(vap1 + (SP) * 4096);                   \
      bf16x8 va2 = *(const bf16x8*)(vap2 + (SP) * 4096);                   \
      bf16x8 va3 = *(const bf16x8*)(vap3 + (SP) * 4096);                   \
      _Pragma("unroll")                                                    \
      for (int mi = 0; mi < 4; ++mi) {                                     \
        oT[mi][0] = __builtin_amdgcn_mfma_f32_16x16x32_bf16(va0, pb[mi], oT[mi][0], 0, 0, 0); \
        oT[mi][1] = __builtin_amdgcn_mfma_f32_16x16x32_bf16(va1, pb[mi], oT[mi][1], 0, 0, 0); \
        oT[mi][2] = __builtin_amdgcn_mfma_f32_16x16x32_bf16(va2, pb[mi], oT[mi][2], 0, 0, 0); \
        oT[mi][3] = __builtin_amdgcn_mfma_f32_16x16x32_bf16(va3, pb[mi], oT[mi][3], 0, 0, 0); \
        oL[mi] = __builtin_amdgcn_mfma_f32_16x16x32_bf16(vone, pb[mi], oL[mi], 0, 0, 0); \
      }                                                                    \
    }                                                                      \
    __builtin_amdgcn_s_setprio(0);                                         \
  } while (0)

  // prologue: stage tiles 0,1,2; retire 0,1 (leave 2 flying); QK(0) -> sxA
  STAGE(0, 0);
  STAGE(1, 1);
  STAGE(2, 2);
  SYNC_VM(4);
  QK4(0, sxA);
  for (int P = 0; P < 16; ++P) {
    int tb = 4 * P;
    // half 1: PV(tb)@s0, QK(tb+1)@s1 || exp(tb), stage(tb+3)->s3
    STAGE(3, (tb + 3) & 63);
    PHASE_A(1, sxB, sxA);
    PHASE_B(0);
    SYNC_VM(4);
    // half 2: PV(tb+1)@s1, QK(tb+2)@s2 || exp(tb+1), stage(tb+4)->s0
    STAGE(0, (tb + 4) & 63);
    PHASE_A(2, sxA, sxB);
    PHASE_B(1);
    SYNC_VM(4);
    // half 3: PV(tb+2)@s2, QK(tb+3)@s3 || exp(tb+2), stage(tb+5)->s1
    STAGE(1, (tb + 5) & 63);
    PHASE_A(3, sxB, sxA);
    PHASE_B(2);
    SYNC_VM(4);
    // half 4: PV(tb+3)@s3, QK(tb+4)@s0 || exp(tb+3), stage(tb+6)->s2
    STAGE(2, (tb + 6) & 63);
    PHASE_A(0, sxA, sxB);
    PHASE_B(3);
    SYNC_VM(4);
  }
  // full drain before reusing LDS as combine scratch (in-flight glds16
  // would stomp it)
  __syncthreads();
#undef STAGE
#undef QK4
#undef PHASE_A
#undef PHASE_B

  // ---- combine key-split partials across wave pairs (ksel 0 <- 1) ----
  float ls[4];
#pragma unroll
  for (int mi = 0; mi < 4; ++mi) {
    float s = oL[mi][0];
    s += __shfl_xor(s, 16, 64);
    s += __shfl_xor(s, 32, 64);
    ls[mi] = s;
  }
  // per-qsel scratch: qsel0 -> Ks region (32 KB), qsel1 -> Vs region.
  // oT at lane stride 17 f32x4 (272 B); ls after (offset 64*68 floats).
  float* xb = (qsel == 0) ? (float*)&Ks[0][0] : (float*)&Vs[0][0];
  float* xl = xb + 64 * 68;
  if (ksel == 1) {
    f32x4* dst = (f32x4*)xb + (size_t)lane * 17;
#pragma unroll
    for (int mi = 0; mi < 4; ++mi)
#pragma unroll
      for (int db = 0; db < 4; ++db) dst[mi * 4 + db] = oT[mi][db];
    float* dl = xl + lane * 4;
#pragma unroll
    for (int mi = 0; mi < 4; ++mi) dl[mi] = ls[mi];
  }
  __syncthreads();
  if (ksel == 0) {
    const f32x4* src = (const f32x4*)xb + (size_t)lane * 17;
    const float* sl = xl + lane * 4;
#pragma unroll
    for (int mi = 0; mi < 4; ++mi) {
      float inv = 1.0f / (ls[mi] + sl[mi]);
      int qrow = q0 + mi * 16 + l15;
#pragma unroll
      for (int db = 0; db < 4; ++db) {
        f32x4 o = oT[mi][db] + src[mi * 4 + db];
        union { bf16x4 v; uint32_t u[2]; } ov;
        ov.u[0] = pack2bf(o[0] * inv, o[1] * inv);
        ov.u[1] = pack2bf(o[2] * inv, o[3] * inv);
        *(bf16x4*)(AT + (size_t)qrow * DIMM + h * 64 + db * 16 + quad * 4) = ov.v;
      }
    }
  }
}

// ---------------- output GEMM: AT (4096x1024) @ Wout^T + bias -> f32 -------
// 1D grid 512, T1 chunked swizzle: each XCD owns 64 contiguous works =
// 8 m-rows x 8 n (A-panels L2-local, 8x reuse).
__global__ __launch_bounds__(256) void gemm_out_kernel(
    const unsigned short* __restrict__ AT, const unsigned short* __restrict__ WOT,
    const float* __restrict__ ba, const float* __restrict__ bx,
    float* __restrict__ out) {
  __shared__ unsigned short As[4 * 2048], Bs[4 * 4096];   // 48 KB
  int bid = blockIdx.x;
  int swz = (bid & 7) * 64 + (bid >> 3);        // bijective: 512 % 8 == 0
  int n0 = (swz & 7) * 128, m0 = (swz >> 3) * 64;
  int s = (m0 >= 2048) ? 1 : 0;                 // 0 = a-stream rows, 1 = x
  const unsigned short* Ag = AT + (size_t)m0 * 1024;
  const unsigned short* Bg = WOT + (size_t)s * 1024 * 1024 + (size_t)n0 * 1024;
  f32x4 acc[2][4];
  gemm64_mainloop(Ag, Bg, As, Bs, acc);
  int t = threadIdx.x, lane = t & 63, wid = t >> 6;
  int wm = (wid >> 1) * 32, wn = (wid & 1) * 64;
  int l15 = lane & 15, quad = lane >> 4;
  const float* bias = s ? bx : ba;
  // d_out = [out_x (2048x1024) | out_a (2048x1024)]
  float* obase = s ? (out + (size_t)(m0 - 2048) * 1024)
                   : (out + (size_t)2048 * 1024 + (size_t)m0 * 1024);
#pragma unroll
  for (int mi = 0; mi < 2; ++mi)
#pragma unroll
    for (int r = 0; r < 4; ++r) {
      int row = wm + mi * 16 + quad * 4 + r;
#pragma unroll
      for (int j = 0; j < 4; ++j) {
        int col = n0 + wn + j * 16 + l15;
        obase[(size_t)row * 1024 + col] = acc[mi][j][r] + bias[col];
      }
    }
}

// ---------------------------------------------------------------------------
extern "C" void kernel_launch(void* const* d_in, const int* in_sizes, int n_in,
                              void* d_out, int out_size, void* d_ws, size_t ws_size,
                              hipStream_t stream) {
  const float* x      = (const float*)d_in[0];
  const float* a      = (const float*)d_in[1];
  const float* g_x    = (const float*)d_in[2];
  const float* g_a    = (const float*)d_in[3];
  const float* Wq_x   = (const float*)d_in[4];
  const float* Wkv_x  = (const float*)d_in[5];
  const float* Wq_a   = (const float*)d_in[6];
  const float* Wkv_a  = (const float*)d_in[7];
  const float* Wout_x = (const float*)d_in[8];
  const float* bout_x = (const float*)d_in[9];
  const float* Wout_a = (const float*)d_in[10];
  const float* bout_a = (const float*)d_in[11];
  float* out = (float*)d_out;

  // workspace (30 MB). AT aliases XN (dead after gemm_qkv).
  char* ws = (char*)d_ws;
  const size_t MB = 1024 * 1024;
  unsigned short* XN   = (unsigned short*)(ws);            // 8 MB
  unsigned short* WQT  = (unsigned short*)(ws + 8 * MB);   // 4 MB
  unsigned short* WKVT = (unsigned short*)(ws + 12 * MB);  // 2 MB
  unsigned short* WOT  = (unsigned short*)(ws + 14 * MB);  // 4 MB
  unsigned short* QB   = (unsigned short*)(ws + 18 * MB);  // 8 MB
  unsigned short* KB   = (unsigned short*)(ws + 26 * MB);  // 2 MB
  unsigned short* VT   = (unsigned short*)(ws + 28 * MB);  // 2 MB
  unsigned short* AT   = XN;                               // alias

  prep_kernel<<<dim3(10240), dim3(256), 0, stream>>>(
      a, x, g_a, g_x, Wq_a, Wq_x, Wkv_a, Wkv_x, Wout_a, Wout_x,
      XN, WQT, WKVT, WOT);
  gemm_qkv_kernel<<<dim3(768), dim3(256), 0, stream>>>(
      XN, WQT, WKVT, QB, KB, VT);
  attn_kernel<<<dim3(512), dim3(256), 0, stream>>>(QB, KB, VT, AT);
  gemm_out_kernel<<<dim3(512), dim3(256), 0, stream>>>(
      AT, WOT, bout_a, bout_x, out);
}